// Round 1
// baseline (1999.640 us; speedup 1.0000x reference)
//
#include <hip/hip_runtime.h>
#include <math.h>

#define TPB 256

constexpr int   B_  = 256;
constexpr int   C_  = 1024;
constexpr int   N_  = 80;
constexpr int   BNr = B_ * N_;                 // 20480 rows for BN
constexpr int   CN  = C_ * N_;                 // 81920
constexpr long  BCN = (long)B_ * C_ * N_;      // 20971520
constexpr int   NN  = N_ * N_;                 // 6400
constexpr int   BNN = B_ * NN;                 // 1638400
constexpr float EPSf = 1e-5f;

__device__ __forceinline__ float leakyf(float v) { return v >= 0.0f ? v : 0.2f * v; }

// ---------------------------------------------------------------------------
// K0: sadj = minmax(adj_param); D = rsqrt(rowsum); adjm[n,m] = D[n]*sadj[m,n]*D[m]
// Also zeroes the loss accumulator. Single block.
// ---------------------------------------------------------------------------
__global__ void k_prep_adj(const float* __restrict__ ap, float* __restrict__ sadj,
                           float* __restrict__ adjm, float* __restrict__ lossa) {
  __shared__ float s[NN];
  __shared__ float red[TPB];
  __shared__ float s_lo, s_hi;
  __shared__ float sD[N_];
  const int t = threadIdx.x;
  float lo = 3.4e38f, hi = -3.4e38f;
  for (int i = t; i < NN; i += TPB) { float v = ap[i]; s[i] = v; lo = fminf(lo, v); hi = fmaxf(hi, v); }
  red[t] = lo; __syncthreads();
  for (int o = 128; o > 0; o >>= 1) { if (t < o) red[t] = fminf(red[t], red[t + o]); __syncthreads(); }
  if (t == 0) s_lo = red[0];
  __syncthreads();
  red[t] = hi; __syncthreads();
  for (int o = 128; o > 0; o >>= 1) { if (t < o) red[t] = fmaxf(red[t], red[t + o]); __syncthreads(); }
  if (t == 0) s_hi = red[0];
  __syncthreads();
  const float inv = 1.0f / (s_hi - s_lo);
  for (int i = t; i < NN; i += TPB) { float v = (s[i] - s_lo) * inv; s[i] = v; sadj[i] = v; }
  __syncthreads();
  if (t < N_) { float sum = 0.f; for (int m = 0; m < N_; ++m) sum += s[t * N_ + m]; sD[t] = rsqrtf(sum); }
  if (t == 0) *lossa = 0.0f;
  __syncthreads();
  for (int i = t; i < NN; i += TPB) { int n = i / N_, m = i % N_; adjm[i] = sD[n] * s[m * N_ + n] * sD[m]; }
}

// ---------------------------------------------------------------------------
// K1: out[row, n] = sum_m A[row*80+m] * Bsm[bofs + n*80 + m]
// rows = 262144 contiguous length-80 vectors. batched=0 -> shared 80x80 matrix,
// batched=1 -> per-batch matrix, bofs = (row/1024)*6400.
// Block: 64 rows; thread (tx,ty) does 4 rows x 5 cols (n = tx + 16u).
// ---------------------------------------------------------------------------
__global__ __launch_bounds__(256) void k_rows_small(const float* __restrict__ A,
                                                    const float* __restrict__ Bsm,
                                                    float* __restrict__ outp, int batched) {
  __shared__ float sA[64][84];
  __shared__ float sB[80][84];
  const int t = threadIdx.x;
  const long row0 = (long)blockIdx.x * 64;
  const float* Ab = A + row0 * N_;
  for (int i = t; i < 64 * N_; i += TPB) sA[i / N_][i % N_] = Ab[i];
  const float* Bb = Bsm + (batched ? (row0 >> 10) * (long)NN : 0);
  for (int i = t; i < NN; i += TPB) sB[i / N_][i % N_] = Bb[i];
  __syncthreads();
  const int tx = t % 16, ty = t / 16;
  float acc[4][5];
#pragma unroll
  for (int i = 0; i < 4; ++i)
#pragma unroll
    for (int u = 0; u < 5; ++u) acc[i][u] = 0.f;
  for (int m = 0; m < N_; m += 4) {
    float4 a[4], b[5];
#pragma unroll
    for (int i = 0; i < 4; ++i) a[i] = *(const float4*)&sA[ty * 4 + i][m];
#pragma unroll
    for (int u = 0; u < 5; ++u) b[u] = *(const float4*)&sB[tx + 16 * u][m];
#pragma unroll
    for (int i = 0; i < 4; ++i)
#pragma unroll
      for (int u = 0; u < 5; ++u)
        acc[i][u] += a[i].x * b[u].x + a[i].y * b[u].y + a[i].z * b[u].z + a[i].w * b[u].w;
  }
  float* ob = outp + row0 * N_;
#pragma unroll
  for (int i = 0; i < 4; ++i)
#pragma unroll
    for (int u = 0; u < 5; ++u)
      ob[(ty * 4 + i) * N_ + tx + 16 * u] = acc[i][u];
}

// ---------------------------------------------------------------------------
// K2: big GEMM with transposed store.
// out[b, o, n] (B,C,N layout) = sum_c A[b, c, n] * W[c*1024 + o]
// A indexed as A[m=(b,n), k=c] with addr b*81920 + k*80 + n. M=20480,N=1024,K=1024.
// Block 64x64, thread 4x4, BK=16.
// ---------------------------------------------------------------------------
__global__ __launch_bounds__(256) void k_gemm_bigT(const float* __restrict__ A,
                                                   const float* __restrict__ W,
                                                   float* __restrict__ outT) {
  __shared__ float sA[16][68];
  __shared__ float sB[16][68];
  const int t = threadIdx.x;
  const int tx = t % 16, ty = t / 16;
  const int bm = blockIdx.y * 64;
  const int bo = blockIdx.x * 64;
  const int ml = t % 64, kl0 = t / 64;
  const int m = bm + ml;
  const int bb = m / N_, n = m % N_;
  const float* Arow = A + (long)bb * CN + n;
  float acc[4][4] = {};
  for (int k0 = 0; k0 < C_; k0 += 16) {
#pragma unroll
    for (int kk = 0; kk < 4; ++kk) {
      const int kl = kl0 + kk * 4;
      sA[kl][ml] = Arow[(long)(k0 + kl) * N_];
      sB[kl][ml] = W[(long)(k0 + kl) * C_ + bo + ml];
    }
    __syncthreads();
#pragma unroll
    for (int k = 0; k < 16; ++k) {
      const float4 av = *(const float4*)&sA[k][ty * 4];
      const float4 bv = *(const float4*)&sB[k][tx * 4];
      acc[0][0] += av.x * bv.x; acc[0][1] += av.x * bv.y; acc[0][2] += av.x * bv.z; acc[0][3] += av.x * bv.w;
      acc[1][0] += av.y * bv.x; acc[1][1] += av.y * bv.y; acc[1][2] += av.y * bv.z; acc[1][3] += av.y * bv.w;
      acc[2][0] += av.z * bv.x; acc[2][1] += av.z * bv.y; acc[2][2] += av.z * bv.z; acc[2][3] += av.z * bv.w;
      acc[3][0] += av.w * bv.x; acc[3][1] += av.w * bv.y; acc[3][2] += av.w * bv.z; acc[3][3] += av.w * bv.w;
    }
    __syncthreads();
  }
  const int m0 = bm + ty * 4;
  const int b2 = m0 / N_, n0 = m0 % N_;   // m0 % 4 == 0 and 80 % 4 == 0 -> all 4 rows in same b
#pragma unroll
  for (int j = 0; j < 4; ++j) {
    const int o = bo + tx * 4 + j;
    float4 v = make_float4(acc[0][j], acc[1][j], acc[2][j], acc[3][j]);
    *(float4*)&outT[(long)b2 * CN + (long)o * N_ + n0] = v;
  }
}

// ---------------------------------------------------------------------------
// K3: BN stats per channel over (b,n), input in (B,C,N) layout.
// ---------------------------------------------------------------------------
__global__ void k_bn_stats(const float* __restrict__ X, float* __restrict__ mu, float* __restrict__ rstd) {
  const int c = blockIdx.x, t = threadIdx.x;
  const float* base = X + (long)c * N_;
  double s = 0.0, sq = 0.0;
  for (int i = t; i < BNr; i += TPB) {
    const int b = i / N_, n = i % N_;
    const float v = base[(long)b * CN + n];
    s += v; sq += (double)v * v;
  }
  __shared__ double rs[TPB], rq[TPB];
  rs[t] = s; rq[t] = sq; __syncthreads();
  for (int o = 128; o > 0; o >>= 1) { if (t < o) { rs[t] += rs[t + o]; rq[t] += rq[t + o]; } __syncthreads(); }
  if (t == 0) {
    const double m = rs[0] / BNr;
    const double var = rq[0] / BNr - m * m;
    mu[c] = (float)m;
    rstd[c] = (float)rsqrt(var + (double)EPSf);
  }
}

// ---------------------------------------------------------------------------
// K4: x2 = x + leaky(bn(hT)) elementwise in (B,C,N).
// ---------------------------------------------------------------------------
__global__ void k_x2(const float* __restrict__ x, const float* __restrict__ hT,
                     const float* __restrict__ g, const float* __restrict__ be,
                     const float* __restrict__ mu, const float* __restrict__ rstd,
                     float* __restrict__ x2) {
  const long i = ((long)blockIdx.x * TPB + threadIdx.x) * 4;
  const int c = (int)((i / N_) % C_);
  const float4 hv = *(const float4*)&hT[i];
  const float4 xv = *(const float4*)&x[i];
  const float gm = g[c] * rstd[c], m = mu[c], bb = be[c];
  float4 o;
  o.x = xv.x + leakyf(gm * (hv.x - m) + bb);
  o.y = xv.y + leakyf(gm * (hv.y - m) + bb);
  o.z = xv.z + leakyf(gm * (hv.z - m) + bb);
  o.w = xv.w + leakyf(gm * (hv.w - m) + bb);
  *(float4*)&x2[i] = o;
}

// ---------------------------------------------------------------------------
// K5: glb0[b,c] = mean over n of x2[b,c,:]. One wave per row.
// ---------------------------------------------------------------------------
__global__ void k_glb0(const float* __restrict__ x2, float* __restrict__ glb0) {
  const int gid = blockIdx.x * TPB + threadIdx.x;
  const int wave = gid >> 6, lane = gid & 63;
  const float* r = x2 + (long)wave * N_;
  float v = r[lane];
  if (lane < 16) v += r[64 + lane];
#pragma unroll
  for (int o = 32; o > 0; o >>= 1) v += __shfl_down(v, o);
  if (lane == 0) glb0[wave] = v * (1.0f / N_);
}

// ---------------------------------------------------------------------------
// K6: small NT GEMM: out[m,n] = sum_k A[m*K+k]*Bm[n*ldb+k] + bias[n].
// M = gridDim.y*64 (rows always valid), Nn may have a ragged tail.
// ---------------------------------------------------------------------------
__global__ __launch_bounds__(256) void k_gemm_nt(const float* __restrict__ A, const float* __restrict__ Bm,
                                                 const float* __restrict__ bias, float* __restrict__ outp,
                                                 int Nn, int K, int ldb) {
  __shared__ float sA[64][20];
  __shared__ float sB[64][20];
  const int t = threadIdx.x, tx = t % 16, ty = t / 16;
  const int bm = blockIdx.y * 64, bn = blockIdx.x * 64;
  const int lr = t / 4, lk = (t % 4) * 4;
  float acc[4][4] = {};
  for (int k0 = 0; k0 < K; k0 += 16) {
    float4 av = *(const float4*)&A[(long)(bm + lr) * K + k0 + lk];
    sA[lr][lk + 0] = av.x; sA[lr][lk + 1] = av.y; sA[lr][lk + 2] = av.z; sA[lr][lk + 3] = av.w;
    float4 bv = make_float4(0.f, 0.f, 0.f, 0.f);
    if (bn + lr < Nn) bv = *(const float4*)&Bm[(long)(bn + lr) * ldb + k0 + lk];
    sB[lr][lk + 0] = bv.x; sB[lr][lk + 1] = bv.y; sB[lr][lk + 2] = bv.z; sB[lr][lk + 3] = bv.w;
    __syncthreads();
#pragma unroll
    for (int k = 0; k < 16; ++k) {
      float a[4], b[4];
#pragma unroll
      for (int i = 0; i < 4; ++i) a[i] = sA[ty * 4 + i][k];
#pragma unroll
      for (int j = 0; j < 4; ++j) b[j] = sB[tx * 4 + j][k];
#pragma unroll
      for (int i = 0; i < 4; ++i)
#pragma unroll
        for (int j = 0; j < 4; ++j) acc[i][j] += a[i] * b[j];
    }
    __syncthreads();
  }
#pragma unroll
  for (int j = 0; j < 4; ++j) {
    const int n = bn + tx * 4 + j;
    if (n < Nn) {
      const float bs = bias[n];
#pragma unroll
      for (int i = 0; i < 4; ++i) outp[(long)(bm + ty * 4 + i) * Nn + n] = acc[i][j] + bs;
    }
  }
}

// ---------------------------------------------------------------------------
// K7: BN over batch (256 rows) per channel + leaky. One block per channel.
// ---------------------------------------------------------------------------
__global__ void k_bng(const float* __restrict__ glb1, const float* __restrict__ gg,
                      const float* __restrict__ gb, float* __restrict__ glbf) {
  const int c = blockIdx.x, t = threadIdx.x;
  const float v = glb1[(long)t * C_ + c];
  __shared__ float rs[TPB], rq[TPB];
  rs[t] = v; rq[t] = v * v; __syncthreads();
  for (int o = 128; o > 0; o >>= 1) { if (t < o) { rs[t] += rs[t + o]; rq[t] += rq[t + o]; } __syncthreads(); }
  __shared__ float sm, sr;
  if (t == 0) { const float m = rs[0] / B_; const float var = rq[0] / B_ - m * m; sm = m; sr = rsqrtf(var + EPSf); }
  __syncthreads();
  glbf[(long)t * C_ + c] = leakyf(gg[c] * (v - sm) * sr + gb[c]);
}

// ---------------------------------------------------------------------------
// K8: dadj[b,o,n] = go[b,o] + sum_c Wco[o, 1024+c] * x2[b,c,n]. One block per b.
// ---------------------------------------------------------------------------
__global__ __launch_bounds__(256) void k_dadj(const float* __restrict__ Wco, const float* __restrict__ x2,
                                              const float* __restrict__ go, float* __restrict__ dadj) {
  const int b = blockIdx.x, t = threadIdx.x;
  const int tx = t % 16, ty = t / 16;
  __shared__ float sW[16][84];   // [k][o]
  __shared__ float sX[16][84];   // [k][n]
  float acc[5][5];
#pragma unroll
  for (int u = 0; u < 5; ++u)
#pragma unroll
    for (int v = 0; v < 5; ++v) acc[u][v] = 0.f;
  const float* x2b = x2 + (long)b * CN;
  for (int k0 = 0; k0 < C_; k0 += 16) {
    for (int i = t; i < 1280; i += TPB) { const int kl = i % 16, o = i / 16; sW[kl][o] = Wco[(long)o * 2048 + C_ + k0 + kl]; }
    for (int i = t; i < 1280; i += TPB) { const int nl = i % N_, kl = i / N_; sX[kl][nl] = x2b[(long)(k0 + kl) * N_ + nl]; }
    __syncthreads();
#pragma unroll
    for (int k = 0; k < 16; ++k) {
      float wv[5], xv[5];
#pragma unroll
      for (int u = 0; u < 5; ++u) wv[u] = sW[k][ty + 16 * u];
#pragma unroll
      for (int v = 0; v < 5; ++v) xv[v] = sX[k][tx + 16 * v];
#pragma unroll
      for (int u = 0; u < 5; ++u)
#pragma unroll
        for (int v = 0; v < 5; ++v) acc[u][v] += wv[u] * xv[v];
    }
    __syncthreads();
  }
  const float* gob = go + b * N_;
  float* db = dadj + (long)b * NN;
#pragma unroll
  for (int u = 0; u < 5; ++u) {
    const float g = gob[ty + 16 * u];
#pragma unroll
    for (int v = 0; v < 5; ++v) db[(ty + 16 * u) * N_ + tx + 16 * v] = acc[u][v] + g;
  }
}

// ---------------------------------------------------------------------------
// K9/K10/K11: global minmax of dadj (2-pass) + normalize in place.
// ---------------------------------------------------------------------------
__global__ void k_minmax1(const float* __restrict__ d, float* __restrict__ bmin, float* __restrict__ bmax) {
  const int t = threadIdx.x;
  float lo = 3.4e38f, hi = -3.4e38f;
  for (long i = (long)blockIdx.x * TPB + t; i < BNN; i += (long)512 * TPB) {
    const float v = d[i]; lo = fminf(lo, v); hi = fmaxf(hi, v);
  }
  __shared__ float rl[TPB], rh[TPB];
  rl[t] = lo; rh[t] = hi; __syncthreads();
  for (int o = 128; o > 0; o >>= 1) { if (t < o) { rl[t] = fminf(rl[t], rl[t + o]); rh[t] = fmaxf(rh[t], rh[t + o]); } __syncthreads(); }
  if (t == 0) { bmin[blockIdx.x] = rl[0]; bmax[blockIdx.x] = rh[0]; }
}

__global__ void k_minmax2(const float* __restrict__ bmin, const float* __restrict__ bmax, float* __restrict__ dmm) {
  const int t = threadIdx.x;
  float lo = fminf(bmin[t], bmin[t + 256]);
  float hi = fmaxf(bmax[t], bmax[t + 256]);
  __shared__ float rl[TPB], rh[TPB];
  rl[t] = lo; rh[t] = hi; __syncthreads();
  for (int o = 128; o > 0; o >>= 1) { if (t < o) { rl[t] = fminf(rl[t], rl[t + o]); rh[t] = fmaxf(rh[t], rh[t + o]); } __syncthreads(); }
  if (t == 0) { dmm[0] = rl[0]; dmm[1] = 1.0f / (rh[0] - rl[0]); }
}

__global__ void k_dadjnorm(float* __restrict__ d, const float* __restrict__ dmm) {
  const long i = ((long)blockIdx.x * TPB + threadIdx.x) * 4;
  const float lo = dmm[0], inv = dmm[1];
  float4 v = *(const float4*)&d[i];
  v.x = (v.x - lo) * inv; v.y = (v.y - lo) * inv; v.z = (v.z - lo) * inv; v.w = (v.w - lo) * inv;
  *(float4*)&d[i] = v;
}

// ---------------------------------------------------------------------------
// K12: loss per batch: ||out1 - out1@dadj/N|| + ||dadj - sadj||_F, atomicAdd.
// ---------------------------------------------------------------------------
__global__ void k_loss(const float* __restrict__ dadj, const float* __restrict__ sadj,
                       const float* __restrict__ out1, float* __restrict__ lossa) {
  const int b = blockIdx.x, t = threadIdx.x;
  const float* db = dadj + (long)b * NN;
  const float* o1 = out1 + b * N_;
  float p2 = 0.f;
  for (int i = t; i < NN; i += TPB) { const float d = db[i] - sadj[i]; p2 += d * d; }
  float p1 = 0.f;
  if (t < N_) {
    float acc = 0.f;
    for (int n = 0; n < N_; ++n) acc += o1[n] * db[n * N_ + t];
    const float d = o1[t] - acc * (1.0f / N_);
    p1 = d * d;
  }
  __shared__ float red[TPB];
  __shared__ float s2;
  red[t] = p2; __syncthreads();
  for (int o = 128; o > 0; o >>= 1) { if (t < o) red[t] += red[t + o]; __syncthreads(); }
  if (t == 0) s2 = red[0];
  __syncthreads();
  red[t] = p1; __syncthreads();
  for (int o = 128; o > 0; o >>= 1) { if (t < o) red[t] += red[t + o]; __syncthreads(); }
  if (t == 0) atomicAdd(lossa, sqrtf(s2) + sqrtf(red[0]));
}

// ---------------------------------------------------------------------------
// K13: tadj[b,n,m] = Dd[n]*dadj[b,m,n]*Dd[m], Dd = rsqrt(rowsum). Block per b.
// ---------------------------------------------------------------------------
__global__ void k_tadj(const float* __restrict__ dadj, float* __restrict__ tadj) {
  const int b = blockIdx.x, t = threadIdx.x;
  __shared__ float s[NN];
  __shared__ float sD[N_];
  const float* db = dadj + (long)b * NN;
  for (int i = t; i < NN; i += TPB) s[i] = db[i];
  __syncthreads();
  if (t < N_) { float sum = 0.f; for (int m = 0; m < N_; ++m) sum += s[t * N_ + m]; sD[t] = rsqrtf(sum); }
  __syncthreads();
  float* tb = tadj + (long)b * NN;
  for (int i = t; i < NN; i += TPB) { const int n = i / N_, m = i % N_; tb[i] = sD[n] * s[m * N_ + n] * sD[m]; }
}

// ---------------------------------------------------------------------------
// K14: final BN + leaky in place on d_out (B,C,N); writes loss scalar.
// ---------------------------------------------------------------------------
__global__ void k_final(float* __restrict__ outp, const float* __restrict__ g, const float* __restrict__ be,
                        const float* __restrict__ mu, const float* __restrict__ rstd,
                        const float* __restrict__ lossa) {
  const long i = ((long)blockIdx.x * TPB + threadIdx.x) * 4;
  const int c = (int)((i / N_) % C_);
  float4 v = *(const float4*)&outp[i];
  const float gm = g[c] * rstd[c], m = mu[c], bb = be[c];
  v.x = leakyf(gm * (v.x - m) + bb);
  v.y = leakyf(gm * (v.y - m) + bb);
  v.z = leakyf(gm * (v.z - m) + bb);
  v.w = leakyf(gm * (v.w - m) + bb);
  *(float4*)&outp[i] = v;
  if (blockIdx.x == 0 && threadIdx.x == 0) outp[BCN] = *lossa;
}

// ---------------------------------------------------------------------------
extern "C" void kernel_launch(void* const* d_in, const int* in_sizes, int n_in,
                              void* d_out, int out_size, void* d_ws, size_t ws_size,
                              hipStream_t stream) {
  const float* x    = (const float*)d_in[0];
  const float* out1 = (const float*)d_in[1];
  const float* ap   = (const float*)d_in[2];
  const float* Ws   = (const float*)d_in[3];
  const float* Wd   = (const float*)d_in[4];
  const float* Wg   = (const float*)d_in[5];
  const float* bg   = (const float*)d_in[6];
  const float* Wco  = (const float*)d_in[7];
  const float* bco  = (const float*)d_in[8];
  const float* bn_g  = (const float*)d_in[9];
  const float* bn_b  = (const float*)d_in[10];
  const float* bng_g = (const float*)d_in[11];
  const float* bng_b = (const float*)d_in[12];
  float* out = (float*)d_out;

  float* w = (float*)d_ws;
  float* sadj  = w;                    // 6400
  float* adjm  = sadj + NN;            // 6400
  float* dadj  = adjm + NN;            // 1638400
  float* tadj  = dadj + BNN;           // 1638400
  float* glb0  = tadj + BNN;           // 262144
  float* glb1  = glb0 + B_ * C_;       // 262144
  float* glbf  = glb1 + B_ * C_;       // 262144
  float* go    = glbf + B_ * C_;       // 20480
  float* mu1   = go + BNr;             // 1024
  float* rstd1 = mu1 + C_;             // 1024
  float* mu2   = rstd1 + C_;           // 1024
  float* rstd2 = mu2 + C_;             // 1024
  float* bmin  = rstd2 + C_;           // 512
  float* bmax  = bmin + 512;           // 512
  float* dmm   = bmax + 512;           // 2
  float* lossa = dmm + 2;              // 1
  float* bufA  = lossa + 1 + 1;        // big scratch (B,C,N), 16B aligned

  // ---- static GCN ----
  k_prep_adj<<<1, TPB, 0, stream>>>(ap, sadj, adjm, lossa);
  // xa = (adj @ x) folded over nodes -> OUT used as scratch
  k_rows_small<<<(B_ * C_) / 64, TPB, 0, stream>>>(x, adjm, out, 0);
  // hT (B,C,N) = xa * Ws  (transposed store)
  k_gemm_bigT<<<dim3(C_ / 64, BNr / 64), TPB, 0, stream>>>(out, Ws, bufA);
  k_bn_stats<<<C_, TPB, 0, stream>>>(bufA, mu1, rstd1);
  // x2 = x + leaky(bn(hT)) -> OUT
  k_x2<<<(int)(BCN / (4 * TPB)), TPB, 0, stream>>>(x, bufA, bn_g, bn_b, mu1, rstd1, out);

  // ---- dynamic graph construction ----
  k_glb0<<<(B_ * C_ * 64) / TPB, TPB, 0, stream>>>(out, glb0);
  k_gemm_nt<<<dim3(C_ / 64, B_ / 64), TPB, 0, stream>>>(glb0, Wg, bg, glb1, C_, C_, C_);
  k_bng<<<C_, TPB, 0, stream>>>(glb1, bng_g, bng_b, glbf);
  k_gemm_nt<<<dim3(2, B_ / 64), TPB, 0, stream>>>(glbf, Wco, bco, go, N_, C_, 2 * C_);
  k_dadj<<<B_, TPB, 0, stream>>>(Wco, out, go, dadj);
  k_minmax1<<<512, TPB, 0, stream>>>(dadj, bmin, bmax);
  k_minmax2<<<1, TPB, 0, stream>>>(bmin, bmax, dmm);
  k_dadjnorm<<<BNN / (4 * TPB), TPB, 0, stream>>>(dadj, dmm);

  // ---- adjacency loss ----
  k_loss<<<B_, TPB, 0, stream>>>(dadj, sadj, out1, lossa);

  // ---- dynamic GCN ----
  k_tadj<<<B_, TPB, 0, stream>>>(dadj, tadj);
  // xt = (tadj @ x2) folded over nodes -> bufA
  k_rows_small<<<(B_ * C_) / 64, TPB, 0, stream>>>(out, tadj, bufA, 1);
  // h2T (B,C,N) = xt * Wd -> OUT
  k_gemm_bigT<<<dim3(C_ / 64, BNr / 64), TPB, 0, stream>>>(bufA, Wd, out);
  k_bn_stats<<<C_, TPB, 0, stream>>>(out, mu2, rstd2);
  k_final<<<(int)(BCN / (4 * TPB)), TPB, 0, stream>>>(out, bn_g, bn_b, mu2, rstd2, lossa);
}

// Round 2
// 1064.802 us; speedup vs baseline: 1.8779x; 1.8779x over previous
//
#include <hip/hip_runtime.h>
#include <hip/hip_bf16.h>
#include <math.h>

#define TPB 256

constexpr int   B_  = 256;
constexpr int   C_  = 1024;
constexpr int   N_  = 80;
constexpr int   BNr = B_ * N_;                 // 20480 rows for BN / GEMM M
constexpr int   CN  = C_ * N_;                 // 81920 (== N_*C_ too)
constexpr long  BCN = (long)B_ * C_ * N_;      // 20971520
constexpr int   NN  = N_ * N_;                 // 6400
constexpr int   BNN = B_ * NN;                 // 1638400
constexpr float EPSf = 1e-5f;

typedef __bf16 bf16x8 __attribute__((ext_vector_type(8)));
typedef float  f32x4  __attribute__((ext_vector_type(4)));

__device__ __forceinline__ float leakyf(float v) { return v >= 0.0f ? v : 0.2f * v; }

__device__ __forceinline__ ushort f2bf(float f) {
  __hip_bfloat16 h = __float2bfloat16(f);
  ushort u; __builtin_memcpy(&u, &h, 2); return u;
}
__device__ __forceinline__ float b2f(ushort u) {
  __hip_bfloat16 h; __builtin_memcpy(&h, &u, 2);
  return __bfloat162float(h);
}

#define GLOBAL_AS __attribute__((address_space(1)))
#define LDS_AS    __attribute__((address_space(3)))
__device__ __forceinline__ void load_lds16(const void* g, void* l) {
  __builtin_amdgcn_global_load_lds((const GLOBAL_AS void*)g, (LDS_AS void*)l, 16, 0, 0);
}

// ---------------------------------------------------------------------------
// K0: sadj = minmax(adj_param); D = rsqrt(rowsum); adjm[n,m] = D[n]*sadj[m,n]*D[m]
// ---------------------------------------------------------------------------
__global__ void k_prep_adj(const float* __restrict__ ap, float* __restrict__ sadj,
                           float* __restrict__ adjm, float* __restrict__ lossa) {
  __shared__ float s[NN];
  __shared__ float red[TPB];
  __shared__ float s_lo, s_hi;
  __shared__ float sD[N_];
  const int t = threadIdx.x;
  float lo = 3.4e38f, hi = -3.4e38f;
  for (int i = t; i < NN; i += TPB) { float v = ap[i]; s[i] = v; lo = fminf(lo, v); hi = fmaxf(hi, v); }
  red[t] = lo; __syncthreads();
  for (int o = 128; o > 0; o >>= 1) { if (t < o) red[t] = fminf(red[t], red[t + o]); __syncthreads(); }
  if (t == 0) s_lo = red[0];
  __syncthreads();
  red[t] = hi; __syncthreads();
  for (int o = 128; o > 0; o >>= 1) { if (t < o) red[t] = fmaxf(red[t], red[t + o]); __syncthreads(); }
  if (t == 0) s_hi = red[0];
  __syncthreads();
  const float inv = 1.0f / (s_hi - s_lo);
  for (int i = t; i < NN; i += TPB) { float v = (s[i] - s_lo) * inv; s[i] = v; sadj[i] = v; }
  __syncthreads();
  if (t < N_) { float sum = 0.f; for (int m = 0; m < N_; ++m) sum += s[t * N_ + m]; sD[t] = rsqrtf(sum); }
  if (t == 0) *lossa = 0.0f;
  __syncthreads();
  for (int i = t; i < NN; i += TPB) { int n = i / N_, m = i % N_; adjm[i] = sD[n] * s[m * N_ + n] * sD[m]; }
}

// ---------------------------------------------------------------------------
// KW: Wt[o][c] = bf16(W[c][o]) — transpose + convert, 32x32 LDS tiles.
// ---------------------------------------------------------------------------
__global__ void k_w_bf_t(const float* __restrict__ W, ushort* __restrict__ Wt) {
  __shared__ float s[32][33];
  const int t = threadIdx.x;
  const int tx = t % 32, ty = t / 32;            // 8 rows per pass
  const int r0 = blockIdx.y * 32, c0 = blockIdx.x * 32;
#pragma unroll
  for (int k = 0; k < 4; ++k) s[ty + 8 * k][tx] = W[(size_t)(r0 + ty + 8 * k) * C_ + c0 + tx];
  __syncthreads();
#pragma unroll
  for (int k = 0; k < 4; ++k) Wt[(size_t)(c0 + ty + 8 * k) * C_ + r0 + tx] = f2bf(s[tx][ty + 8 * k]);
}

// ---------------------------------------------------------------------------
// K1v2: out_bf16[(b*80+n)*1024 + c] = sum_m adj[n,m] * A[b,c,m]   (A in B,C,N fp32)
// mode 0: adj = Bsm (shared 80x80). mode 1: adj = tadj(dadj[b]) computed in LDS:
//   tadj[n][m] = Dd[n]*dadj[m][n]*Dd[m], Dd[n] = rsqrt(sum_m dadj[n][m]).
// Block: 64 rows (one b, 64 consecutive c). Output is MFMA-ready (B,N,C) bf16.
// ---------------------------------------------------------------------------
__global__ __launch_bounds__(256) void k_rows_small_v2(const float* __restrict__ A,
                                                       const float* __restrict__ Bsm,
                                                       ushort* __restrict__ outp, int mode) {
  __shared__ float sA[64][84];
  __shared__ float sB[80][84];
  __shared__ float sD[N_];
  const int t = threadIdx.x;
  const long row0 = (long)blockIdx.x * 64;       // rows = (b,c), 64 c's of one b
  const int b  = (int)(row0 >> 10);
  const int c0 = (int)(row0 & 1023);
  const float* Ab = A + row0 * N_;
  for (int i4 = t; i4 < (64 * N_) / 4; i4 += TPB) {
    float4 v = *(const float4*)&Ab[i4 * 4];
    *(float4*)&sA[(i4 * 4) / N_][(i4 * 4) % N_] = v;
  }
  if (mode == 0) {
    for (int i4 = t; i4 < NN / 4; i4 += TPB) {
      float4 v = *(const float4*)&Bsm[i4 * 4];
      *(float4*)&sB[(i4 * 4) / N_][(i4 * 4) % N_] = v;
    }
    __syncthreads();
  } else {
    const float* db = Bsm + (size_t)b * NN;
    for (int i4 = t; i4 < NN / 4; i4 += TPB) {   // sB[n][m] = dadj[m][n]
      float4 v = *(const float4*)&db[i4 * 4];
      const int m = (i4 * 4) / N_, n = (i4 * 4) % N_;
      sB[n + 0][m] = v.x; sB[n + 1][m] = v.y; sB[n + 2][m] = v.z; sB[n + 3][m] = v.w;
    }
    __syncthreads();
    if (t < N_) { float s = 0.f; for (int m = 0; m < N_; ++m) s += sB[m][t]; sD[t] = rsqrtf(s); }
    __syncthreads();
    for (int i = t; i < NN; i += TPB) { const int n = i / N_, m = i % N_; sB[n][m] *= sD[n] * sD[m]; }
    __syncthreads();
  }
  const int tx = t % 16, ty = t / 16;
  float acc[4][5];
#pragma unroll
  for (int i = 0; i < 4; ++i)
#pragma unroll
    for (int u = 0; u < 5; ++u) acc[i][u] = 0.f;
  for (int m = 0; m < N_; m += 4) {
    float4 a[4], bv[5];
#pragma unroll
    for (int i = 0; i < 4; ++i) a[i] = *(const float4*)&sA[ty * 4 + i][m];
#pragma unroll
    for (int u = 0; u < 5; ++u) bv[u] = *(const float4*)&sB[tx + 16 * u][m];
#pragma unroll
    for (int i = 0; i < 4; ++i)
#pragma unroll
      for (int u = 0; u < 5; ++u)
        acc[i][u] += a[i].x * bv[u].x + a[i].y * bv[u].y + a[i].z * bv[u].z + a[i].w * bv[u].w;
  }
  ushort* ob = outp + (size_t)b * CN + c0;
#pragma unroll
  for (int u = 0; u < 5; ++u) {
    const int n = tx + 16 * u;
    ushort4 v;
    v.x = f2bf(acc[0][u]); v.y = f2bf(acc[1][u]); v.z = f2bf(acc[2][u]); v.w = f2bf(acc[3][u]);
    *(ushort4*)&ob[(size_t)n * C_ + ty * 4] = v;
  }
}

// ---------------------------------------------------------------------------
// K2: MFMA GEMM. A: (M=20480) x (K=1024) bf16 row-major (== xa in B,N,C).
// Bt: (O=1024) x (K=1024) bf16 row-major (transposed weight).
// out[b, o, n] (B,C,N) = sum_k A[m=(b,n)][k] * Bt[o][k];  out_bf: 1 -> bf16 store.
// 128x128 tile, 4 waves (2x2 of 64x64), 16x16x32 MFMA, BK=32, global_load_lds x16.
// ---------------------------------------------------------------------------
__global__ __launch_bounds__(256) void k_gemm_mfma(const ushort* __restrict__ A,
                                                   const ushort* __restrict__ Bt,
                                                   void* __restrict__ outp, int out_bf) {
  __shared__ ushort smA[128 * 32];
  __shared__ ushort smB[128 * 32];
  const int t = threadIdx.x;
  const int lane = t & 63, wid = t >> 6;
  const int m0 = blockIdx.y * 128, o0 = blockIdx.x * 128;
  const int wm = wid & 1, wn = wid >> 1;
  const int rto = t >> 2, ch = t & 3;            // staging: row-in-64, 16B chunk
  const size_t gA0 = (size_t)(m0 + rto) * C_ + (size_t)ch * 8;
  const size_t gB0 = (size_t)(o0 + rto) * C_ + (size_t)ch * 8;
  ushort* ldsA = smA + wid * 512;                // wave-uniform LDS bases
  ushort* ldsB = smB + wid * 512;
  const int l16 = lane & 15, lq = lane >> 4;
  const int raOff = (wm * 64 + l16) * 32 + lq * 8;
  const int rbOff = (wn * 64 + l16) * 32 + lq * 8;
  f32x4 zero = {0.f, 0.f, 0.f, 0.f};
  f32x4 acc[4][4];
#pragma unroll
  for (int i = 0; i < 4; ++i)
#pragma unroll
    for (int j = 0; j < 4; ++j) acc[i][j] = zero;
  for (int k0 = 0; k0 < C_; k0 += 32) {
    load_lds16(A  + gA0 + k0,              ldsA);
    load_lds16(A  + gA0 + 64 * C_ + k0,    ldsA + 2048);
    load_lds16(Bt + gB0 + k0,              ldsB);
    load_lds16(Bt + gB0 + 64 * C_ + k0,    ldsB + 2048);
    __syncthreads();
    bf16x8 af[4], bfr[4];
#pragma unroll
    for (int i = 0; i < 4; ++i) af[i]  = *(const bf16x8*)&smA[raOff + i * 512];
#pragma unroll
    for (int j = 0; j < 4; ++j) bfr[j] = *(const bf16x8*)&smB[rbOff + j * 512];
#pragma unroll
    for (int i = 0; i < 4; ++i)
#pragma unroll
      for (int j = 0; j < 4; ++j)
        acc[i][j] = __builtin_amdgcn_mfma_f32_16x16x32_bf16(af[i], bfr[j], acc[i][j], 0, 0, 0);
    __syncthreads();
  }
  // Epilogue: D row = m (lq*4+reg) -> 4 consecutive n in one b; D col = o (l16).
  const int og0 = o0 + wn * 64 + l16;
#pragma unroll
  for (int i = 0; i < 4; ++i) {
    const int mg = m0 + wm * 64 + i * 16 + lq * 4;
    const int b  = mg / 80;
    const int n0 = mg - b * 80;
#pragma unroll
    for (int j = 0; j < 4; ++j) {
      const int og = og0 + j * 16;
      const size_t off = (size_t)b * CN + (size_t)og * N_ + n0;
      if (out_bf) {
        ushort4 v;
        v.x = f2bf(acc[i][j][0]); v.y = f2bf(acc[i][j][1]);
        v.z = f2bf(acc[i][j][2]); v.w = f2bf(acc[i][j][3]);
        *(ushort4*)((ushort*)outp + off) = v;
      } else {
        *(f32x4*)((float*)outp + off) = acc[i][j];
      }
    }
  }
}

// ---------------------------------------------------------------------------
// K3: BN stats per channel over (b,n) — fp32 (B,C,N) input.
// ---------------------------------------------------------------------------
__global__ void k_bn_stats(const float* __restrict__ X, float* __restrict__ mu, float* __restrict__ rstd) {
  const int c = blockIdx.x, t = threadIdx.x;
  const float* base = X + (long)c * N_;
  double s = 0.0, sq = 0.0;
  for (int i = t; i < BNr; i += TPB) {
    const int b = i / N_, n = i % N_;
    const float v = base[(long)b * CN + n];
    s += v; sq += (double)v * v;
  }
  __shared__ double rs[TPB], rq[TPB];
  rs[t] = s; rq[t] = sq; __syncthreads();
  for (int o = 128; o > 0; o >>= 1) { if (t < o) { rs[t] += rs[t + o]; rq[t] += rq[t + o]; } __syncthreads(); }
  if (t == 0) {
    const double m = rs[0] / BNr;
    const double var = rq[0] / BNr - m * m;
    mu[c] = (float)m;
    rstd[c] = (float)rsqrt(var + (double)EPSf);
  }
}

// K3b: same, bf16 (B,C,N) input.
__global__ void k_bn_stats_bf(const ushort* __restrict__ X, float* __restrict__ mu, float* __restrict__ rstd) {
  const int c = blockIdx.x, t = threadIdx.x;
  const ushort* base = X + (long)c * N_;
  double s = 0.0, sq = 0.0;
  for (int i4 = t; i4 < BNr / 4; i4 += TPB) {
    const int b = i4 / 20, n0 = (i4 % 20) * 4;
    ushort4 v = *(const ushort4*)&base[(long)b * CN + n0];
    const float f0 = b2f(v.x), f1 = b2f(v.y), f2 = b2f(v.z), f3 = b2f(v.w);
    s += (double)f0 + (double)f1 + (double)f2 + (double)f3;
    sq += (double)f0 * f0 + (double)f1 * f1 + (double)f2 * f2 + (double)f3 * f3;
  }
  __shared__ double rs[TPB], rq[TPB];
  rs[t] = s; rq[t] = sq; __syncthreads();
  for (int o = 128; o > 0; o >>= 1) { if (t < o) { rs[t] += rs[t + o]; rq[t] += rq[t + o]; } __syncthreads(); }
  if (t == 0) {
    const double m = rs[0] / BNr;
    const double var = rq[0] / BNr - m * m;
    mu[c] = (float)m;
    rstd[c] = (float)rsqrt(var + (double)EPSf);
  }
}

// ---------------------------------------------------------------------------
// K4: x2 = x + leaky(bn(hT_bf16)) elementwise in (B,C,N).
// ---------------------------------------------------------------------------
__global__ void k_x2(const float* __restrict__ x, const ushort* __restrict__ hT,
                     const float* __restrict__ g, const float* __restrict__ be,
                     const float* __restrict__ mu, const float* __restrict__ rstd,
                     float* __restrict__ x2) {
  const long i = ((long)blockIdx.x * TPB + threadIdx.x) * 4;
  const int c = (int)((i / N_) % C_);
  ushort4 hu = *(const ushort4*)&hT[i];
  const float4 xv = *(const float4*)&x[i];
  const float gm = g[c] * rstd[c], m = mu[c], bb = be[c];
  float4 o;
  o.x = xv.x + leakyf(gm * (b2f(hu.x) - m) + bb);
  o.y = xv.y + leakyf(gm * (b2f(hu.y) - m) + bb);
  o.z = xv.z + leakyf(gm * (b2f(hu.z) - m) + bb);
  o.w = xv.w + leakyf(gm * (b2f(hu.w) - m) + bb);
  *(float4*)&x2[i] = o;
}

// ---------------------------------------------------------------------------
// K5: glb0[b,c] = mean over n of x2[b,c,:]. One wave per row.
// ---------------------------------------------------------------------------
__global__ void k_glb0(const float* __restrict__ x2, float* __restrict__ glb0) {
  const int gid = blockIdx.x * TPB + threadIdx.x;
  const int wave = gid >> 6, lane = gid & 63;
  const float* r = x2 + (long)wave * N_;
  float v = r[lane];
  if (lane < 16) v += r[64 + lane];
#pragma unroll
  for (int o = 32; o > 0; o >>= 1) v += __shfl_down(v, o);
  if (lane == 0) glb0[wave] = v * (1.0f / N_);
}

// ---------------------------------------------------------------------------
// K6: small NT GEMM: out[m,n] = sum_k A[m*K+k]*Bm[n*ldb+k] + bias[n].
// ---------------------------------------------------------------------------
__global__ __launch_bounds__(256) void k_gemm_nt(const float* __restrict__ A, const float* __restrict__ Bm,
                                                 const float* __restrict__ bias, float* __restrict__ outp,
                                                 int Nn, int K, int ldb) {
  __shared__ float sA[64][20];
  __shared__ float sB[64][20];
  const int t = threadIdx.x, tx = t % 16, ty = t / 16;
  const int bm = blockIdx.y * 64, bn = blockIdx.x * 64;
  const int lr = t / 4, lk = (t % 4) * 4;
  float acc[4][4] = {};
  for (int k0 = 0; k0 < K; k0 += 16) {
    float4 av = *(const float4*)&A[(long)(bm + lr) * K + k0 + lk];
    sA[lr][lk + 0] = av.x; sA[lr][lk + 1] = av.y; sA[lr][lk + 2] = av.z; sA[lr][lk + 3] = av.w;
    float4 bv = make_float4(0.f, 0.f, 0.f, 0.f);
    if (bn + lr < Nn) bv = *(const float4*)&Bm[(long)(bn + lr) * ldb + k0 + lk];
    sB[lr][lk + 0] = bv.x; sB[lr][lk + 1] = bv.y; sB[lr][lk + 2] = bv.z; sB[lr][lk + 3] = bv.w;
    __syncthreads();
#pragma unroll
    for (int k = 0; k < 16; ++k) {
      float a[4], b[4];
#pragma unroll
      for (int i = 0; i < 4; ++i) a[i] = sA[ty * 4 + i][k];
#pragma unroll
      for (int j = 0; j < 4; ++j) b[j] = sB[tx * 4 + j][k];
#pragma unroll
      for (int i = 0; i < 4; ++i)
#pragma unroll
        for (int j = 0; j < 4; ++j) acc[i][j] += a[i] * b[j];
    }
    __syncthreads();
  }
#pragma unroll
  for (int j = 0; j < 4; ++j) {
    const int n = bn + tx * 4 + j;
    if (n < Nn) {
      const float bs = bias[n];
#pragma unroll
      for (int i = 0; i < 4; ++i) outp[(long)(bm + ty * 4 + i) * Nn + n] = acc[i][j] + bs;
    }
  }
}

// ---------------------------------------------------------------------------
// K7: BN over batch (256 rows) per channel + leaky.
// ---------------------------------------------------------------------------
__global__ void k_bng(const float* __restrict__ glb1, const float* __restrict__ gg,
                      const float* __restrict__ gb, float* __restrict__ glbf) {
  const int c = blockIdx.x, t = threadIdx.x;
  const float v = glb1[(long)t * C_ + c];
  __shared__ float rs[TPB], rq[TPB];
  rs[t] = v; rq[t] = v * v; __syncthreads();
  for (int o = 128; o > 0; o >>= 1) { if (t < o) { rs[t] += rs[t + o]; rq[t] += rq[t + o]; } __syncthreads(); }
  __shared__ float sm, sr;
  if (t == 0) { const float m = rs[0] / B_; const float var = rq[0] / B_ - m * m; sm = m; sr = rsqrtf(var + EPSf); }
  __syncthreads();
  glbf[(long)t * C_ + c] = leakyf(gg[c] * (v - sm) * sr + gb[c]);
}

// ---------------------------------------------------------------------------
// K8: dadj[b,o,n] = go[b,o] + sum_c Wco[o, 1024+c] * x2[b,c,n]. One block per b.
// ---------------------------------------------------------------------------
__global__ __launch_bounds__(256) void k_dadj(const float* __restrict__ Wco, const float* __restrict__ x2,
                                              const float* __restrict__ go, float* __restrict__ dadj) {
  const int b = blockIdx.x, t = threadIdx.x;
  const int tx = t % 16, ty = t / 16;
  __shared__ float sW[16][84];
  __shared__ float sX[16][84];
  float acc[5][5];
#pragma unroll
  for (int u = 0; u < 5; ++u)
#pragma unroll
    for (int v = 0; v < 5; ++v) acc[u][v] = 0.f;
  const float* x2b = x2 + (long)b * CN;
  for (int k0 = 0; k0 < C_; k0 += 16) {
    for (int i = t; i < 1280; i += TPB) { const int kl = i % 16, o = i / 16; sW[kl][o] = Wco[(long)o * 2048 + C_ + k0 + kl]; }
    for (int i = t; i < 1280; i += TPB) { const int nl = i % N_, kl = i / N_; sX[kl][nl] = x2b[(long)(k0 + kl) * N_ + nl]; }
    __syncthreads();
#pragma unroll
    for (int k = 0; k < 16; ++k) {
      float wv[5], xv[5];
#pragma unroll
      for (int u = 0; u < 5; ++u) wv[u] = sW[k][ty + 16 * u];
#pragma unroll
      for (int v = 0; v < 5; ++v) xv[v] = sX[k][tx + 16 * v];
#pragma unroll
      for (int u = 0; u < 5; ++u)
#pragma unroll
        for (int v = 0; v < 5; ++v) acc[u][v] += wv[u] * xv[v];
    }
    __syncthreads();
  }
  const float* gob = go + b * N_;
  float* db = dadj + (long)b * NN;
#pragma unroll
  for (int u = 0; u < 5; ++u) {
    const float g = gob[ty + 16 * u];
#pragma unroll
    for (int v = 0; v < 5; ++v) db[(ty + 16 * u) * N_ + tx + 16 * v] = acc[u][v] + g;
  }
}

// ---------------------------------------------------------------------------
// K9/K10/K11: global minmax of dadj (2-pass) + normalize in place.
// ---------------------------------------------------------------------------
__global__ void k_minmax1(const float* __restrict__ d, float* __restrict__ bmin, float* __restrict__ bmax) {
  const int t = threadIdx.x;
  float lo = 3.4e38f, hi = -3.4e38f;
  for (long i = (long)blockIdx.x * TPB + t; i < BNN; i += (long)512 * TPB) {
    const float v = d[i]; lo = fminf(lo, v); hi = fmaxf(hi, v);
  }
  __shared__ float rl[TPB], rh[TPB];
  rl[t] = lo; rh[t] = hi; __syncthreads();
  for (int o = 128; o > 0; o >>= 1) { if (t < o) { rl[t] = fminf(rl[t], rl[t + o]); rh[t] = fmaxf(rh[t], rh[t + o]); } __syncthreads(); }
  if (t == 0) { bmin[blockIdx.x] = rl[0]; bmax[blockIdx.x] = rh[0]; }
}

__global__ void k_minmax2(const float* __restrict__ bmin, const float* __restrict__ bmax, float* __restrict__ dmm) {
  const int t = threadIdx.x;
  float lo = fminf(bmin[t], bmin[t + 256]);
  float hi = fmaxf(bmax[t], bmax[t + 256]);
  __shared__ float rl[TPB], rh[TPB];
  rl[t] = lo; rh[t] = hi; __syncthreads();
  for (int o = 128; o > 0; o >>= 1) { if (t < o) { rl[t] = fminf(rl[t], rl[t + o]); rh[t] = fmaxf(rh[t], rh[t + o]); } __syncthreads(); }
  if (t == 0) { dmm[0] = rl[0]; dmm[1] = 1.0f / (rh[0] - rl[0]); }
}

__global__ void k_dadjnorm(float* __restrict__ d, const float* __restrict__ dmm) {
  const long i = ((long)blockIdx.x * TPB + threadIdx.x) * 4;
  const float lo = dmm[0], inv = dmm[1];
  float4 v = *(const float4*)&d[i];
  v.x = (v.x - lo) * inv; v.y = (v.y - lo) * inv; v.z = (v.z - lo) * inv; v.w = (v.w - lo) * inv;
  *(float4*)&d[i] = v;
}

// ---------------------------------------------------------------------------
// K12: loss per batch.
// ---------------------------------------------------------------------------
__global__ void k_loss(const float* __restrict__ dadj, const float* __restrict__ sadj,
                       const float* __restrict__ out1, float* __restrict__ lossa) {
  const int b = blockIdx.x, t = threadIdx.x;
  const float* db = dadj + (long)b * NN;
  const float* o1 = out1 + b * N_;
  float p2 = 0.f;
  for (int i = t; i < NN; i += TPB) { const float d = db[i] - sadj[i]; p2 += d * d; }
  float p1 = 0.f;
  if (t < N_) {
    float acc = 0.f;
    for (int n = 0; n < N_; ++n) acc += o1[n] * db[n * N_ + t];
    const float d = o1[t] - acc * (1.0f / N_);
    p1 = d * d;
  }
  __shared__ float red[TPB];
  __shared__ float s2;
  red[t] = p2; __syncthreads();
  for (int o = 128; o > 0; o >>= 1) { if (t < o) red[t] += red[t + o]; __syncthreads(); }
  if (t == 0) s2 = red[0];
  __syncthreads();
  red[t] = p1; __syncthreads();
  for (int o = 128; o > 0; o >>= 1) { if (t < o) red[t] += red[t + o]; __syncthreads(); }
  if (t == 0) atomicAdd(lossa, sqrtf(s2) + sqrtf(red[0]));
}

// ---------------------------------------------------------------------------
// K14: final BN + leaky in place on d_out (B,C,N); writes loss scalar.
// ---------------------------------------------------------------------------
__global__ void k_final(float* __restrict__ outp, const float* __restrict__ g, const float* __restrict__ be,
                        const float* __restrict__ mu, const float* __restrict__ rstd,
                        const float* __restrict__ lossa) {
  const long i = ((long)blockIdx.x * TPB + threadIdx.x) * 4;
  const int c = (int)((i / N_) % C_);
  float4 v = *(const float4*)&outp[i];
  const float gm = g[c] * rstd[c], m = mu[c], bb = be[c];
  v.x = leakyf(gm * (v.x - m) + bb);
  v.y = leakyf(gm * (v.y - m) + bb);
  v.z = leakyf(gm * (v.z - m) + bb);
  v.w = leakyf(gm * (v.w - m) + bb);
  *(float4*)&outp[i] = v;
  if (blockIdx.x == 0 && threadIdx.x == 0) outp[BCN] = *lossa;
}

// ---------------------------------------------------------------------------
extern "C" void kernel_launch(void* const* d_in, const int* in_sizes, int n_in,
                              void* d_out, int out_size, void* d_ws, size_t ws_size,
                              hipStream_t stream) {
  const float* x    = (const float*)d_in[0];
  const float* out1 = (const float*)d_in[1];
  const float* ap   = (const float*)d_in[2];
  const float* Ws   = (const float*)d_in[3];
  const float* Wd   = (const float*)d_in[4];
  const float* Wg   = (const float*)d_in[5];
  const float* bg   = (const float*)d_in[6];
  const float* Wco  = (const float*)d_in[7];
  const float* bco  = (const float*)d_in[8];
  const float* bn_g  = (const float*)d_in[9];
  const float* bn_b  = (const float*)d_in[10];
  const float* bng_g = (const float*)d_in[11];
  const float* bng_b = (const float*)d_in[12];
  float* out = (float*)d_out;

  float* w = (float*)d_ws;
  float* sadj  = w;                    // 6400
  float* adjm  = sadj + NN;            // 6400
  float* dadj  = adjm + NN;            // 1638400
  float* glb0  = dadj + BNN;           // 262144
  float* glb1  = glb0 + B_ * C_;       // 262144
  float* glbf  = glb1 + B_ * C_;       // 262144
  float* go    = glbf + B_ * C_;       // 20480
  float* mu1   = go + BNr;             // 1024
  float* rstd1 = mu1 + C_;             // 1024
  float* mu2   = rstd1 + C_;           // 1024
  float* rstd2 = mu2 + C_;             // 1024
  float* bmin  = rstd2 + C_;           // 512
  float* bmax  = bmin + 512;           // 512
  float* dmm   = bmax + 512;           // 2
  float* lossa = dmm + 2;              // 1
  ushort* ub   = (ushort*)(((uintptr_t)(lossa + 1) + 255) & ~(uintptr_t)255);
  ushort* xa_bf = ub;                  // BCN bf16 (B,N,C) — also reused for xt
  ushort* hT_bf = xa_bf + BCN;         // BCN bf16 (B,C,N)
  ushort* Wts   = hT_bf + BCN;         // 1M bf16 (O,C)
  ushort* Wtd   = Wts + (size_t)C_ * C_; // 1M bf16 (O,C)

  // ---- prep ----
  k_prep_adj<<<1, TPB, 0, stream>>>(ap, sadj, adjm, lossa);
  k_w_bf_t<<<dim3(32, 32), TPB, 0, stream>>>(Ws, Wts);
  k_w_bf_t<<<dim3(32, 32), TPB, 0, stream>>>(Wd, Wtd);

  // ---- static GCN ----
  k_rows_small_v2<<<(B_ * C_) / 64, TPB, 0, stream>>>(x, adjm, xa_bf, 0);
  k_gemm_mfma<<<dim3(C_ / 128, BNr / 128), TPB, 0, stream>>>(xa_bf, Wts, hT_bf, 1);
  k_bn_stats_bf<<<C_, TPB, 0, stream>>>(hT_bf, mu1, rstd1);
  k_x2<<<(int)(BCN / (4 * TPB)), TPB, 0, stream>>>(x, hT_bf, bn_g, bn_b, mu1, rstd1, out);

  // ---- dynamic graph construction ----
  k_glb0<<<(B_ * C_ * 64) / TPB, TPB, 0, stream>>>(out, glb0);
  k_gemm_nt<<<dim3(C_ / 64, B_ / 64), TPB, 0, stream>>>(glb0, Wg, bg, glb1, C_, C_, C_);
  k_bng<<<C_, TPB, 0, stream>>>(glb1, bng_g, bng_b, glbf);
  k_gemm_nt<<<dim3(2, B_ / 64), TPB, 0, stream>>>(glbf, Wco, bco, go, N_, C_, 2 * C_);
  k_dadj<<<B_, TPB, 0, stream>>>(Wco, out, go, dadj);
  k_minmax1<<<512, TPB, 0, stream>>>(dadj, bmin, bmax);
  k_minmax2<<<1, TPB, 0, stream>>>(bmin, bmax, dmm);
  k_dadjnorm<<<BNN / (4 * TPB), TPB, 0, stream>>>(dadj, dmm);

  // ---- adjacency loss ----
  k_loss<<<B_, TPB, 0, stream>>>(dadj, sadj, out1, lossa);

  // ---- dynamic GCN ----
  k_rows_small_v2<<<(B_ * C_) / 64, TPB, 0, stream>>>(out, dadj, xa_bf, 1);  // tadj folded in
  k_gemm_mfma<<<dim3(C_ / 128, BNr / 128), TPB, 0, stream>>>(xa_bf, Wtd, out, 0);
  k_bn_stats<<<C_, TPB, 0, stream>>>(out, mu2, rstd2);
  k_final<<<(int)(BCN / (4 * TPB)), TPB, 0, stream>>>(out, bn_g, bn_b, mu2, rstd2, lossa);
}

// Round 3
// 861.675 us; speedup vs baseline: 2.3206x; 1.2357x over previous
//
#include <hip/hip_runtime.h>
#include <hip/hip_bf16.h>
#include <math.h>

#define TPB 256

constexpr int   B_  = 256;
constexpr int   C_  = 1024;
constexpr int   N_  = 80;
constexpr int   BNr = B_ * N_;                 // 20480 rows for BN / GEMM M
constexpr int   CN  = C_ * N_;                 // 81920
constexpr long  BCN = (long)B_ * C_ * N_;      // 20971520
constexpr int   NN  = N_ * N_;                 // 6400
constexpr int   BNN = B_ * NN;                 // 1638400
constexpr float EPSf = 1e-5f;

typedef __bf16 bf16x8 __attribute__((ext_vector_type(8)));
typedef float  f32x4  __attribute__((ext_vector_type(4)));

__device__ __forceinline__ float leakyf(float v) { return v >= 0.0f ? v : 0.2f * v; }

__device__ __forceinline__ ushort f2bf(float f) {
  __hip_bfloat16 h = __float2bfloat16(f);
  ushort u; __builtin_memcpy(&u, &h, 2); return u;
}
__device__ __forceinline__ float b2f(ushort u) {
  __hip_bfloat16 h; __builtin_memcpy(&h, &u, 2);
  return __bfloat162float(h);
}

#define GLOBAL_AS __attribute__((address_space(1)))
#define LDS_AS    __attribute__((address_space(3)))
__device__ __forceinline__ void load_lds16(const void* g, void* l) {
  __builtin_amdgcn_global_load_lds((const GLOBAL_AS void*)g, (LDS_AS void*)l, 16, 0, 0);
}

// ---------------------------------------------------------------------------
// K0: sadj = minmax(adj_param); D = rsqrt(rowsum); adjm[n,m] = D[n]*sadj[m,n]*D[m]
// ---------------------------------------------------------------------------
__global__ void k_prep_adj(const float* __restrict__ ap, float* __restrict__ sadj,
                           float* __restrict__ adjm, float* __restrict__ lossa) {
  __shared__ float s[NN];
  __shared__ float red[TPB];
  __shared__ float s_lo, s_hi;
  __shared__ float sD[N_];
  const int t = threadIdx.x;
  float lo = 3.4e38f, hi = -3.4e38f;
  for (int i = t; i < NN; i += TPB) { float v = ap[i]; s[i] = v; lo = fminf(lo, v); hi = fmaxf(hi, v); }
  red[t] = lo; __syncthreads();
  for (int o = 128; o > 0; o >>= 1) { if (t < o) red[t] = fminf(red[t], red[t + o]); __syncthreads(); }
  if (t == 0) s_lo = red[0];
  __syncthreads();
  red[t] = hi; __syncthreads();
  for (int o = 128; o > 0; o >>= 1) { if (t < o) red[t] = fmaxf(red[t], red[t + o]); __syncthreads(); }
  if (t == 0) s_hi = red[0];
  __syncthreads();
  const float inv = 1.0f / (s_hi - s_lo);
  for (int i = t; i < NN; i += TPB) { float v = (s[i] - s_lo) * inv; s[i] = v; sadj[i] = v; }
  __syncthreads();
  if (t < N_) { float sum = 0.f; for (int m = 0; m < N_; ++m) sum += s[t * N_ + m]; sD[t] = rsqrtf(sum); }
  if (t == 0) *lossa = 0.0f;
  __syncthreads();
  for (int i = t; i < NN; i += TPB) { int n = i / N_, m = i % N_; adjm[i] = sD[n] * s[m * N_ + n] * sD[m]; }
}

// ---------------------------------------------------------------------------
// KW: Wt[o][c] = bf16(W[c][o]) — transpose + convert, 32x32 LDS tiles.
// ---------------------------------------------------------------------------
__global__ void k_w_bf_t(const float* __restrict__ W, ushort* __restrict__ Wt) {
  __shared__ float s[32][33];
  const int t = threadIdx.x;
  const int tx = t % 32, ty = t / 32;            // 8 rows per pass
  const int r0 = blockIdx.y * 32, c0 = blockIdx.x * 32;
#pragma unroll
  for (int k = 0; k < 4; ++k) s[ty + 8 * k][tx] = W[(size_t)(r0 + ty + 8 * k) * C_ + c0 + tx];
  __syncthreads();
#pragma unroll
  for (int k = 0; k < 4; ++k) Wt[(size_t)(c0 + ty + 8 * k) * C_ + r0 + tx] = f2bf(s[tx][ty + 8 * k]);
}

// ---------------------------------------------------------------------------
// KW2: Wco2t[o][c] = bf16(Wco[o][1024+c]), o<80, c<1024.
// ---------------------------------------------------------------------------
__global__ void k_wco2_bf(const float* __restrict__ Wco, ushort* __restrict__ Wco2t) {
  const int i4 = (blockIdx.x * TPB + threadIdx.x) * 4;   // 80*1024 elems
  const int o = i4 >> 10, c = i4 & 1023;
  float4 v = *(const float4*)&Wco[(size_t)o * 2048 + C_ + c];
  ushort4 u;
  u.x = f2bf(v.x); u.y = f2bf(v.y); u.z = f2bf(v.z); u.w = f2bf(v.w);
  *(ushort4*)&Wco2t[(size_t)o * C_ + c] = u;
}

// ---------------------------------------------------------------------------
// K1v2: out_bf16[(b*80+n)*1024 + c] = sum_m adj[n,m] * A[b,c,m]   (A in B,C,N fp32)
// mode 0: adj = Bsm (shared 80x80). mode 1: adj = tadj(dadj[b]) computed in LDS.
// ---------------------------------------------------------------------------
__global__ __launch_bounds__(256) void k_rows_small_v2(const float* __restrict__ A,
                                                       const float* __restrict__ Bsm,
                                                       ushort* __restrict__ outp, int mode) {
  __shared__ float sA[64][84];
  __shared__ float sB[80][84];
  __shared__ float sD[N_];
  const int t = threadIdx.x;
  const long row0 = (long)blockIdx.x * 64;       // rows = (b,c), 64 c's of one b
  const int b  = (int)(row0 >> 10);
  const int c0 = (int)(row0 & 1023);
  const float* Ab = A + row0 * N_;
  for (int i4 = t; i4 < (64 * N_) / 4; i4 += TPB) {
    float4 v = *(const float4*)&Ab[i4 * 4];
    *(float4*)&sA[(i4 * 4) / N_][(i4 * 4) % N_] = v;
  }
  if (mode == 0) {
    for (int i4 = t; i4 < NN / 4; i4 += TPB) {
      float4 v = *(const float4*)&Bsm[i4 * 4];
      *(float4*)&sB[(i4 * 4) / N_][(i4 * 4) % N_] = v;
    }
    __syncthreads();
  } else {
    const float* db = Bsm + (size_t)b * NN;
    for (int i4 = t; i4 < NN / 4; i4 += TPB) {   // sB[n][m] = dadj[m][n]
      float4 v = *(const float4*)&db[i4 * 4];
      const int m = (i4 * 4) / N_, n = (i4 * 4) % N_;
      sB[n + 0][m] = v.x; sB[n + 1][m] = v.y; sB[n + 2][m] = v.z; sB[n + 3][m] = v.w;
    }
    __syncthreads();
    if (t < N_) { float s = 0.f; for (int m = 0; m < N_; ++m) s += sB[m][t]; sD[t] = rsqrtf(s); }
    __syncthreads();
    for (int i = t; i < NN; i += TPB) { const int n = i / N_, m = i % N_; sB[n][m] *= sD[n] * sD[m]; }
    __syncthreads();
  }
  const int tx = t % 16, ty = t / 16;
  float acc[4][5];
#pragma unroll
  for (int i = 0; i < 4; ++i)
#pragma unroll
    for (int u = 0; u < 5; ++u) acc[i][u] = 0.f;
  for (int m = 0; m < N_; m += 4) {
    float4 a[4], bv[5];
#pragma unroll
    for (int i = 0; i < 4; ++i) a[i] = *(const float4*)&sA[ty * 4 + i][m];
#pragma unroll
    for (int u = 0; u < 5; ++u) bv[u] = *(const float4*)&sB[tx + 16 * u][m];
#pragma unroll
    for (int i = 0; i < 4; ++i)
#pragma unroll
      for (int u = 0; u < 5; ++u)
        acc[i][u] += a[i].x * bv[u].x + a[i].y * bv[u].y + a[i].z * bv[u].z + a[i].w * bv[u].w;
  }
  ushort* ob = outp + (size_t)b * CN + c0;
#pragma unroll
  for (int u = 0; u < 5; ++u) {
    const int n = tx + 16 * u;
    ushort4 v;
    v.x = f2bf(acc[0][u]); v.y = f2bf(acc[1][u]); v.z = f2bf(acc[2][u]); v.w = f2bf(acc[3][u]);
    *(ushort4*)&ob[(size_t)n * C_ + ty * 4] = v;
  }
}

// ---------------------------------------------------------------------------
// K2: MFMA GEMM. A: 20480 x 1024 bf16 row-major. Bt: 1024 x 1024 bf16 row-major.
// out[b, o, n] (B,C,N) = sum_k A[m=(b,n)][k] * Bt[o][k];  out_bf: 1 -> bf16 store.
// ---------------------------------------------------------------------------
__global__ __launch_bounds__(256) void k_gemm_mfma(const ushort* __restrict__ A,
                                                   const ushort* __restrict__ Bt,
                                                   void* __restrict__ outp, int out_bf) {
  __shared__ ushort smA[128 * 32];
  __shared__ ushort smB[128 * 32];
  const int t = threadIdx.x;
  const int lane = t & 63, wid = t >> 6;
  const int m0 = blockIdx.y * 128, o0 = blockIdx.x * 128;
  const int wm = wid & 1, wn = wid >> 1;
  const int rto = t >> 2, ch = t & 3;
  const size_t gA0 = (size_t)(m0 + rto) * C_ + (size_t)ch * 8;
  const size_t gB0 = (size_t)(o0 + rto) * C_ + (size_t)ch * 8;
  ushort* ldsA = smA + wid * 512;
  ushort* ldsB = smB + wid * 512;
  const int l16 = lane & 15, lq = lane >> 4;
  const int raOff = (wm * 64 + l16) * 32 + lq * 8;
  const int rbOff = (wn * 64 + l16) * 32 + lq * 8;
  f32x4 zero = {0.f, 0.f, 0.f, 0.f};
  f32x4 acc[4][4];
#pragma unroll
  for (int i = 0; i < 4; ++i)
#pragma unroll
    for (int j = 0; j < 4; ++j) acc[i][j] = zero;
  for (int k0 = 0; k0 < C_; k0 += 32) {
    load_lds16(A  + gA0 + k0,              ldsA);
    load_lds16(A  + gA0 + 64 * C_ + k0,    ldsA + 2048);
    load_lds16(Bt + gB0 + k0,              ldsB);
    load_lds16(Bt + gB0 + 64 * C_ + k0,    ldsB + 2048);
    __syncthreads();
    bf16x8 af[4], bfr[4];
#pragma unroll
    for (int i = 0; i < 4; ++i) af[i]  = *(const bf16x8*)&smA[raOff + i * 512];
#pragma unroll
    for (int j = 0; j < 4; ++j) bfr[j] = *(const bf16x8*)&smB[rbOff + j * 512];
#pragma unroll
    for (int i = 0; i < 4; ++i)
#pragma unroll
      for (int j = 0; j < 4; ++j)
        acc[i][j] = __builtin_amdgcn_mfma_f32_16x16x32_bf16(af[i], bfr[j], acc[i][j], 0, 0, 0);
    __syncthreads();
  }
  const int og0 = o0 + wn * 64 + l16;
#pragma unroll
  for (int i = 0; i < 4; ++i) {
    const int mg = m0 + wm * 64 + i * 16 + lq * 4;
    const int b  = mg / 80;
    const int n0 = mg - b * 80;
#pragma unroll
    for (int j = 0; j < 4; ++j) {
      const int og = og0 + j * 16;
      const size_t off = (size_t)b * CN + (size_t)og * N_ + n0;
      if (out_bf) {
        ushort4 v;
        v.x = f2bf(acc[i][j][0]); v.y = f2bf(acc[i][j][1]);
        v.z = f2bf(acc[i][j][2]); v.w = f2bf(acc[i][j][3]);
        *(ushort4*)((ushort*)outp + off) = v;
      } else {
        *(f32x4*)((float*)outp + off) = acc[i][j];
      }
    }
  }
}

// ---------------------------------------------------------------------------
// K2b: dadj MFMA GEMM. A: x2t bf16 (M=20480, K=1024). Bw: Wco2t bf16 (80,1024).
// dadj[b,o,n] = go[b,o] + sum_k A[m=(b,n)][k]*Bw[o][k]. 128-row tile, 160 blocks.
// ---------------------------------------------------------------------------
__global__ __launch_bounds__(256) void k_dadj_mfma(const ushort* __restrict__ A,
                                                   const ushort* __restrict__ Bw,
                                                   const float* __restrict__ go,
                                                   float* __restrict__ dadj) {
  __shared__ ushort smA[128 * 32];
  __shared__ ushort smB[80 * 32];
  const int t = threadIdx.x;
  const int lane = t & 63, wid = t >> 6;
  const int m0 = blockIdx.x * 128;
  const int rto = t >> 2, ch = t & 3;
  const size_t gA0 = (size_t)(m0 + rto) * C_ + (size_t)ch * 8;
  ushort* ldsA = smA + wid * 512;
  const int l16 = lane & 15, lq = lane >> 4;
  const int wrow = wid * 32;
  f32x4 zero = {0.f, 0.f, 0.f, 0.f};
  f32x4 acc[2][5];
#pragma unroll
  for (int i = 0; i < 2; ++i)
#pragma unroll
    for (int j = 0; j < 5; ++j) acc[i][j] = zero;
  for (int k0 = 0; k0 < C_; k0 += 32) {
    load_lds16(A + gA0 + k0,            ldsA);
    load_lds16(A + gA0 + 64 * C_ + k0,  ldsA + 2048);
    {
      const int idx = t;                               // 320 chunks of 16B
      uint4 v = *(const uint4*)&Bw[(size_t)(idx >> 2) * C_ + k0 + (idx & 3) * 8];
      *(uint4*)&smB[idx * 8] = v;
      if (t < 64) {
        const int idx2 = 256 + t;
        uint4 v2 = *(const uint4*)&Bw[(size_t)(idx2 >> 2) * C_ + k0 + (idx2 & 3) * 8];
        *(uint4*)&smB[idx2 * 8] = v2;
      }
    }
    __syncthreads();
    bf16x8 af[2], bfr[5];
#pragma unroll
    for (int i = 0; i < 2; ++i) af[i]  = *(const bf16x8*)&smA[(wrow + i * 16 + l16) * 32 + lq * 8];
#pragma unroll
    for (int j = 0; j < 5; ++j) bfr[j] = *(const bf16x8*)&smB[(j * 16 + l16) * 32 + lq * 8];
#pragma unroll
    for (int i = 0; i < 2; ++i)
#pragma unroll
      for (int j = 0; j < 5; ++j)
        acc[i][j] = __builtin_amdgcn_mfma_f32_16x16x32_bf16(af[i], bfr[j], acc[i][j], 0, 0, 0);
    __syncthreads();
  }
#pragma unroll
  for (int i = 0; i < 2; ++i) {
    const int mg = m0 + wrow + i * 16 + lq * 4;
    const int b  = mg / 80;
    const int n0 = mg - b * 80;
    const float* gob = go + b * N_;
#pragma unroll
    for (int j = 0; j < 5; ++j) {
      const int o = j * 16 + l16;
      const float g = gob[o];
      f32x4 v = acc[i][j];
      v[0] += g; v[1] += g; v[2] += g; v[3] += g;
      *(f32x4*)&dadj[(size_t)b * NN + (size_t)o * N_ + n0] = v;
    }
  }
}

// ---------------------------------------------------------------------------
// K3: BN stats per channel over (b,n) — fp32 (B,C,N) input.
// ---------------------------------------------------------------------------
__global__ void k_bn_stats(const float* __restrict__ X, float* __restrict__ mu, float* __restrict__ rstd) {
  const int c = blockIdx.x, t = threadIdx.x;
  const float* base = X + (long)c * N_;
  double s = 0.0, sq = 0.0;
  for (int i = t; i < BNr; i += TPB) {
    const int b = i / N_, n = i % N_;
    const float v = base[(long)b * CN + n];
    s += v; sq += (double)v * v;
  }
  __shared__ double rs[TPB], rq[TPB];
  rs[t] = s; rq[t] = sq; __syncthreads();
  for (int o = 128; o > 0; o >>= 1) { if (t < o) { rs[t] += rs[t + o]; rq[t] += rq[t + o]; } __syncthreads(); }
  if (t == 0) {
    const double m = rs[0] / BNr;
    const double var = rq[0] / BNr - m * m;
    mu[c] = (float)m;
    rstd[c] = (float)rsqrt(var + (double)EPSf);
  }
}

// K3b: same, bf16 (B,C,N) input.
__global__ void k_bn_stats_bf(const ushort* __restrict__ X, float* __restrict__ mu, float* __restrict__ rstd) {
  const int c = blockIdx.x, t = threadIdx.x;
  const ushort* base = X + (long)c * N_;
  double s = 0.0, sq = 0.0;
  for (int i4 = t; i4 < BNr / 4; i4 += TPB) {
    const int b = i4 / 20, n0 = (i4 % 20) * 4;
    ushort4 v = *(const ushort4*)&base[(long)b * CN + n0];
    const float f0 = b2f(v.x), f1 = b2f(v.y), f2 = b2f(v.z), f3 = b2f(v.w);
    s += (double)f0 + (double)f1 + (double)f2 + (double)f3;
    sq += (double)f0 * f0 + (double)f1 * f1 + (double)f2 * f2 + (double)f3 * f3;
  }
  __shared__ double rs[TPB], rq[TPB];
  rs[t] = s; rq[t] = sq; __syncthreads();
  for (int o = 128; o > 0; o >>= 1) { if (t < o) { rs[t] += rs[t + o]; rq[t] += rq[t + o]; } __syncthreads(); }
  if (t == 0) {
    const double m = rs[0] / BNr;
    const double var = rq[0] / BNr - m * m;
    mu[c] = (float)m;
    rstd[c] = (float)rsqrt(var + (double)EPSf);
  }
}

// ---------------------------------------------------------------------------
// K4: x2 = x + leaky(bn(hT_bf16)) elementwise in (B,C,N).
// ---------------------------------------------------------------------------
__global__ void k_x2(const float* __restrict__ x, const ushort* __restrict__ hT,
                     const float* __restrict__ g, const float* __restrict__ be,
                     const float* __restrict__ mu, const float* __restrict__ rstd,
                     float* __restrict__ x2) {
  const long i = ((long)blockIdx.x * TPB + threadIdx.x) * 4;
  const int c = (int)((i / N_) % C_);
  ushort4 hu = *(const ushort4*)&hT[i];
  const float4 xv = *(const float4*)&x[i];
  const float gm = g[c] * rstd[c], m = mu[c], bb = be[c];
  float4 o;
  o.x = xv.x + leakyf(gm * (b2f(hu.x) - m) + bb);
  o.y = xv.y + leakyf(gm * (b2f(hu.y) - m) + bb);
  o.z = xv.z + leakyf(gm * (b2f(hu.z) - m) + bb);
  o.w = xv.w + leakyf(gm * (b2f(hu.w) - m) + bb);
  *(float4*)&x2[i] = o;
}

// ---------------------------------------------------------------------------
// K4b: x2t[b,n,c] = bf16(x2[b,c,n]) — transpose to MFMA A layout.
// ---------------------------------------------------------------------------
__global__ __launch_bounds__(256) void k_x2t(const float* __restrict__ x2, ushort* __restrict__ x2t) {
  __shared__ float s[64][84];
  const int t = threadIdx.x;
  const long row0 = (long)blockIdx.x * 64;
  const int b = (int)(row0 >> 10), c0 = (int)(row0 & 1023);
  const float* Ab = x2 + row0 * N_;
  for (int i4 = t; i4 < (64 * N_) / 4; i4 += TPB) {
    float4 v = *(const float4*)&Ab[i4 * 4];
    *(float4*)&s[(i4 * 4) / N_][(i4 * 4) % N_] = v;
  }
  __syncthreads();
  const int tx = t % 16, ty = t / 16;
  ushort* ob = x2t + (size_t)b * CN + c0 + tx * 4;
#pragma unroll
  for (int u = 0; u < 5; ++u) {
    const int n = ty + 16 * u;
    ushort4 v;
    v.x = f2bf(s[tx * 4 + 0][n]); v.y = f2bf(s[tx * 4 + 1][n]);
    v.z = f2bf(s[tx * 4 + 2][n]); v.w = f2bf(s[tx * 4 + 3][n]);
    *(ushort4*)&ob[(size_t)n * C_] = v;
  }
}

// ---------------------------------------------------------------------------
// K5: glb0[b,c] = mean over n of x2[b,c,:]. One wave per row.
// ---------------------------------------------------------------------------
__global__ void k_glb0(const float* __restrict__ x2, float* __restrict__ glb0) {
  const int gid = blockIdx.x * TPB + threadIdx.x;
  const int wave = gid >> 6, lane = gid & 63;
  const float* r = x2 + (long)wave * N_;
  float v = r[lane];
  if (lane < 16) v += r[64 + lane];
#pragma unroll
  for (int o = 32; o > 0; o >>= 1) v += __shfl_down(v, o);
  if (lane == 0) glb0[wave] = v * (1.0f / N_);
}

// ---------------------------------------------------------------------------
// K6: small NT GEMM: out[m,n] = sum_k A[m*K+k]*Bm[n*ldb+k] + bias[n].
// ---------------------------------------------------------------------------
__global__ __launch_bounds__(256) void k_gemm_nt(const float* __restrict__ A, const float* __restrict__ Bm,
                                                 const float* __restrict__ bias, float* __restrict__ outp,
                                                 int Nn, int K, int ldb) {
  __shared__ float sA[64][20];
  __shared__ float sB[64][20];
  const int t = threadIdx.x, tx = t % 16, ty = t / 16;
  const int bm = blockIdx.y * 64, bn = blockIdx.x * 64;
  const int lr = t / 4, lk = (t % 4) * 4;
  float acc[4][4] = {};
  for (int k0 = 0; k0 < K; k0 += 16) {
    float4 av = *(const float4*)&A[(long)(bm + lr) * K + k0 + lk];
    sA[lr][lk + 0] = av.x; sA[lr][lk + 1] = av.y; sA[lr][lk + 2] = av.z; sA[lr][lk + 3] = av.w;
    float4 bv = make_float4(0.f, 0.f, 0.f, 0.f);
    if (bn + lr < Nn) bv = *(const float4*)&Bm[(long)(bn + lr) * ldb + k0 + lk];
    sB[lr][lk + 0] = bv.x; sB[lr][lk + 1] = bv.y; sB[lr][lk + 2] = bv.z; sB[lr][lk + 3] = bv.w;
    __syncthreads();
#pragma unroll
    for (int k = 0; k < 16; ++k) {
      float a[4], b[4];
#pragma unroll
      for (int i = 0; i < 4; ++i) a[i] = sA[ty * 4 + i][k];
#pragma unroll
      for (int j = 0; j < 4; ++j) b[j] = sB[tx * 4 + j][k];
#pragma unroll
      for (int i = 0; i < 4; ++i)
#pragma unroll
        for (int j = 0; j < 4; ++j) acc[i][j] += a[i] * b[j];
    }
    __syncthreads();
  }
#pragma unroll
  for (int j = 0; j < 4; ++j) {
    const int n = bn + tx * 4 + j;
    if (n < Nn) {
      const float bs = bias[n];
#pragma unroll
      for (int i = 0; i < 4; ++i) outp[(long)(bm + ty * 4 + i) * Nn + n] = acc[i][j] + bs;
    }
  }
}

// ---------------------------------------------------------------------------
// K7: BN over batch (256 rows) per channel + leaky.
// ---------------------------------------------------------------------------
__global__ void k_bng(const float* __restrict__ glb1, const float* __restrict__ gg,
                      const float* __restrict__ gb, float* __restrict__ glbf) {
  const int c = blockIdx.x, t = threadIdx.x;
  const float v = glb1[(long)t * C_ + c];
  __shared__ float rs[TPB], rq[TPB];
  rs[t] = v; rq[t] = v * v; __syncthreads();
  for (int o = 128; o > 0; o >>= 1) { if (t < o) { rs[t] += rs[t + o]; rq[t] += rq[t + o]; } __syncthreads(); }
  __shared__ float sm, sr;
  if (t == 0) { const float m = rs[0] / B_; const float var = rq[0] / B_ - m * m; sm = m; sr = rsqrtf(var + EPSf); }
  __syncthreads();
  glbf[(long)t * C_ + c] = leakyf(gg[c] * (v - sm) * sr + gb[c]);
}

// ---------------------------------------------------------------------------
// K9/K10/K11: global minmax of dadj (2-pass) + normalize in place.
// ---------------------------------------------------------------------------
__global__ void k_minmax1(const float* __restrict__ d, float* __restrict__ bmin, float* __restrict__ bmax) {
  const int t = threadIdx.x;
  float lo = 3.4e38f, hi = -3.4e38f;
  for (long i = (long)blockIdx.x * TPB + t; i < BNN; i += (long)512 * TPB) {
    const float v = d[i]; lo = fminf(lo, v); hi = fmaxf(hi, v);
  }
  __shared__ float rl[TPB], rh[TPB];
  rl[t] = lo; rh[t] = hi; __syncthreads();
  for (int o = 128; o > 0; o >>= 1) { if (t < o) { rl[t] = fminf(rl[t], rl[t + o]); rh[t] = fmaxf(rh[t], rh[t + o]); } __syncthreads(); }
  if (t == 0) { bmin[blockIdx.x] = rl[0]; bmax[blockIdx.x] = rh[0]; }
}

__global__ void k_minmax2(const float* __restrict__ bmin, const float* __restrict__ bmax, float* __restrict__ dmm) {
  const int t = threadIdx.x;
  float lo = fminf(bmin[t], bmin[t + 256]);
  float hi = fmaxf(bmax[t], bmax[t + 256]);
  __shared__ float rl[TPB], rh[TPB];
  rl[t] = lo; rh[t] = hi; __syncthreads();
  for (int o = 128; o > 0; o >>= 1) { if (t < o) { rl[t] = fminf(rl[t], rl[t + o]); rh[t] = fmaxf(rh[t], rh[t + o]); } __syncthreads(); }
  if (t == 0) { dmm[0] = rl[0]; dmm[1] = 1.0f / (rh[0] - rl[0]); }
}

__global__ void k_dadjnorm(float* __restrict__ d, const float* __restrict__ dmm) {
  const long i = ((long)blockIdx.x * TPB + threadIdx.x) * 4;
  const float lo = dmm[0], inv = dmm[1];
  float4 v = *(const float4*)&d[i];
  v.x = (v.x - lo) * inv; v.y = (v.y - lo) * inv; v.z = (v.z - lo) * inv; v.w = (v.w - lo) * inv;
  *(float4*)&d[i] = v;
}

// ---------------------------------------------------------------------------
// K12: loss per batch.
// ---------------------------------------------------------------------------
__global__ void k_loss(const float* __restrict__ dadj, const float* __restrict__ sadj,
                       const float* __restrict__ out1, float* __restrict__ lossa) {
  const int b = blockIdx.x, t = threadIdx.x;
  const float* db = dadj + (long)b * NN;
  const float* o1 = out1 + b * N_;
  float p2 = 0.f;
  for (int i = t; i < NN; i += TPB) { const float d = db[i] - sadj[i]; p2 += d * d; }
  float p1 = 0.f;
  if (t < N_) {
    float acc = 0.f;
    for (int n = 0; n < N_; ++n) acc += o1[n] * db[n * N_ + t];
    const float d = o1[t] - acc * (1.0f / N_);
    p1 = d * d;
  }
  __shared__ float red[TPB];
  __shared__ float s2;
  red[t] = p2; __syncthreads();
  for (int o = 128; o > 0; o >>= 1) { if (t < o) red[t] += red[t + o]; __syncthreads(); }
  if (t == 0) s2 = red[0];
  __syncthreads();
  red[t] = p1; __syncthreads();
  for (int o = 128; o > 0; o >>= 1) { if (t < o) red[t] += red[t + o]; __syncthreads(); }
  if (t == 0) atomicAdd(lossa, sqrtf(s2) + sqrtf(red[0]));
}

// ---------------------------------------------------------------------------
// K14: final BN + leaky in place on d_out (B,C,N); writes loss scalar.
// ---------------------------------------------------------------------------
__global__ void k_final(float* __restrict__ outp, const float* __restrict__ g, const float* __restrict__ be,
                        const float* __restrict__ mu, const float* __restrict__ rstd,
                        const float* __restrict__ lossa) {
  const long i = ((long)blockIdx.x * TPB + threadIdx.x) * 4;
  const int c = (int)((i / N_) % C_);
  float4 v = *(const float4*)&outp[i];
  const float gm = g[c] * rstd[c], m = mu[c], bb = be[c];
  v.x = leakyf(gm * (v.x - m) + bb);
  v.y = leakyf(gm * (v.y - m) + bb);
  v.z = leakyf(gm * (v.z - m) + bb);
  v.w = leakyf(gm * (v.w - m) + bb);
  *(float4*)&outp[i] = v;
  if (blockIdx.x == 0 && threadIdx.x == 0) outp[BCN] = *lossa;
}

// ---------------------------------------------------------------------------
extern "C" void kernel_launch(void* const* d_in, const int* in_sizes, int n_in,
                              void* d_out, int out_size, void* d_ws, size_t ws_size,
                              hipStream_t stream) {
  const float* x    = (const float*)d_in[0];
  const float* out1 = (const float*)d_in[1];
  const float* ap   = (const float*)d_in[2];
  const float* Ws   = (const float*)d_in[3];
  const float* Wd   = (const float*)d_in[4];
  const float* Wg   = (const float*)d_in[5];
  const float* bg   = (const float*)d_in[6];
  const float* Wco  = (const float*)d_in[7];
  const float* bco  = (const float*)d_in[8];
  const float* bn_g  = (const float*)d_in[9];
  const float* bn_b  = (const float*)d_in[10];
  const float* bng_g = (const float*)d_in[11];
  const float* bng_b = (const float*)d_in[12];
  float* out = (float*)d_out;

  float* w = (float*)d_ws;
  float* sadj  = w;                    // 6400
  float* adjm  = sadj + NN;            // 6400
  float* dadj  = adjm + NN;            // 1638400
  float* glb0  = dadj + BNN;           // 262144
  float* glb1  = glb0 + B_ * C_;       // 262144
  float* glbf  = glb1 + B_ * C_;       // 262144
  float* go    = glbf + B_ * C_;       // 20480
  float* mu1   = go + BNr;             // 1024
  float* rstd1 = mu1 + C_;             // 1024
  float* mu2   = rstd1 + C_;           // 1024
  float* rstd2 = mu2 + C_;             // 1024
  float* bmin  = rstd2 + C_;           // 512
  float* bmax  = bmin + 512;           // 512
  float* dmm   = bmax + 512;           // 2
  float* lossa = dmm + 2;              // 1
  ushort* ub   = (ushort*)(((uintptr_t)(lossa + 1) + 255) & ~(uintptr_t)255);
  ushort* xa_bf = ub;                    // BCN bf16 (B,N,C) — reused for xt
  ushort* hT_bf = xa_bf + BCN;           // BCN bf16 (B,C,N); later reused as x2t
  ushort* Wts   = hT_bf + BCN;           // 1M bf16 (O,C)
  ushort* Wtd   = Wts + (size_t)C_ * C_; // 1M bf16 (O,C)
  ushort* Wco2t = Wtd + (size_t)C_ * C_; // 80K bf16 (80,1024)
  ushort* x2t_bf = hT_bf;                // alias: hT dead after k_x2

  // ---- prep ----
  k_prep_adj<<<1, TPB, 0, stream>>>(ap, sadj, adjm, lossa);
  k_w_bf_t<<<dim3(32, 32), TPB, 0, stream>>>(Ws, Wts);
  k_w_bf_t<<<dim3(32, 32), TPB, 0, stream>>>(Wd, Wtd);
  k_wco2_bf<<<(N_ * C_) / (4 * TPB), TPB, 0, stream>>>(Wco, Wco2t);

  // ---- static GCN ----
  k_rows_small_v2<<<(B_ * C_) / 64, TPB, 0, stream>>>(x, adjm, xa_bf, 0);
  k_gemm_mfma<<<dim3(C_ / 128, BNr / 128), TPB, 0, stream>>>(xa_bf, Wts, hT_bf, 1);
  k_bn_stats_bf<<<C_, TPB, 0, stream>>>(hT_bf, mu1, rstd1);
  k_x2<<<(int)(BCN / (4 * TPB)), TPB, 0, stream>>>(x, hT_bf, bn_g, bn_b, mu1, rstd1, out);

  // ---- dynamic graph construction ----
  k_x2t<<<(B_ * C_) / 64, TPB, 0, stream>>>(out, x2t_bf);
  k_glb0<<<(B_ * C_ * 64) / TPB, TPB, 0, stream>>>(out, glb0);
  k_gemm_nt<<<dim3(C_ / 64, B_ / 64), TPB, 0, stream>>>(glb0, Wg, bg, glb1, C_, C_, C_);
  k_bng<<<C_, TPB, 0, stream>>>(glb1, bng_g, bng_b, glbf);
  k_gemm_nt<<<dim3(2, B_ / 64), TPB, 0, stream>>>(glbf, Wco, bco, go, N_, C_, 2 * C_);
  k_dadj_mfma<<<BNr / 128, TPB, 0, stream>>>(x2t_bf, Wco2t, go, dadj);
  k_minmax1<<<512, TPB, 0, stream>>>(dadj, bmin, bmax);
  k_minmax2<<<1, TPB, 0, stream>>>(bmin, bmax, dmm);
  k_dadjnorm<<<BNN / (4 * TPB), TPB, 0, stream>>>(dadj, dmm);

  // ---- adjacency loss ----
  k_loss<<<B_, TPB, 0, stream>>>(dadj, sadj, out1, lossa);

  // ---- dynamic GCN ----
  k_rows_small_v2<<<(B_ * C_) / 64, TPB, 0, stream>>>(out, dadj, xa_bf, 1);  // tadj folded in
  k_gemm_mfma<<<dim3(C_ / 128, BNr / 128), TPB, 0, stream>>>(xa_bf, Wtd, out, 0);
  k_bn_stats<<<C_, TPB, 0, stream>>>(out, mu2, rstd2);
  k_final<<<(int)(BCN / (4 * TPB)), TPB, 0, stream>>>(out, bn_g, bn_b, mu2, rstd2, lossa);
}

// Round 4
// 790.672 us; speedup vs baseline: 2.5290x; 1.0898x over previous
//
#include <hip/hip_runtime.h>
#include <hip/hip_bf16.h>
#include <math.h>

#define TPB 256

constexpr int   B_  = 256;
constexpr int   C_  = 1024;
constexpr int   N_  = 80;
constexpr int   BNr = B_ * N_;                 // 20480 rows for BN / GEMM M
constexpr int   CN  = C_ * N_;                 // 81920
constexpr long  BCN = (long)B_ * C_ * N_;      // 20971520
constexpr int   NN  = N_ * N_;                 // 6400
constexpr int   BNN = B_ * NN;                 // 1638400
constexpr float EPSf = 1e-5f;

typedef __bf16 bf16x8 __attribute__((ext_vector_type(8)));
typedef float  f32x4  __attribute__((ext_vector_type(4)));

__device__ __forceinline__ float leakyf(float v) { return v >= 0.0f ? v : 0.2f * v; }

__device__ __forceinline__ ushort f2bf(float f) {
  __hip_bfloat16 h = __float2bfloat16(f);
  ushort u; __builtin_memcpy(&u, &h, 2); return u;
}
__device__ __forceinline__ float b2f(ushort u) {
  __hip_bfloat16 h; __builtin_memcpy(&h, &u, 2);
  return __bfloat162float(h);
}

#define GLOBAL_AS __attribute__((address_space(1)))
#define LDS_AS    __attribute__((address_space(3)))
__device__ __forceinline__ void load_lds16(const void* g, void* l) {
  __builtin_amdgcn_global_load_lds((const GLOBAL_AS void*)g, (LDS_AS void*)l, 16, 0, 0);
}

// ---------------------------------------------------------------------------
// K0: sadj = minmax(adj_param); D = rsqrt(rowsum);
// adj_bf[n*96+m] = bf16(D[n]*sadj[m,n]*D[m]) for m<80, 0 for m in [80,96).
// ---------------------------------------------------------------------------
__global__ void k_prep_adj(const float* __restrict__ ap, float* __restrict__ sadj,
                           ushort* __restrict__ adj_bf, float* __restrict__ lossa) {
  __shared__ float s[NN];
  __shared__ float red[TPB];
  __shared__ float s_lo, s_hi;
  __shared__ float sD[N_];
  const int t = threadIdx.x;
  float lo = 3.4e38f, hi = -3.4e38f;
  for (int i = t; i < NN; i += TPB) { float v = ap[i]; s[i] = v; lo = fminf(lo, v); hi = fmaxf(hi, v); }
  red[t] = lo; __syncthreads();
  for (int o = 128; o > 0; o >>= 1) { if (t < o) red[t] = fminf(red[t], red[t + o]); __syncthreads(); }
  if (t == 0) s_lo = red[0];
  __syncthreads();
  red[t] = hi; __syncthreads();
  for (int o = 128; o > 0; o >>= 1) { if (t < o) red[t] = fmaxf(red[t], red[t + o]); __syncthreads(); }
  if (t == 0) s_hi = red[0];
  __syncthreads();
  const float inv = 1.0f / (s_hi - s_lo);
  for (int i = t; i < NN; i += TPB) { float v = (s[i] - s_lo) * inv; s[i] = v; sadj[i] = v; }
  __syncthreads();
  if (t < N_) { float sum = 0.f; for (int m = 0; m < N_; ++m) sum += s[t * N_ + m]; sD[t] = rsqrtf(sum); }
  if (t == 0) *lossa = 0.0f;
  __syncthreads();
  for (int i = t; i < N_ * 96; i += TPB) {
    const int n = i / 96, m = i % 96;
    adj_bf[i] = f2bf((m < N_) ? sD[n] * s[m * N_ + n] * sD[m] : 0.0f);
  }
}

// ---------------------------------------------------------------------------
// KW: Wt[o][c] = bf16(W[c][o]) — transpose + convert, 32x32 LDS tiles.
// ---------------------------------------------------------------------------
__global__ void k_w_bf_t(const float* __restrict__ W, ushort* __restrict__ Wt) {
  __shared__ float s[32][33];
  const int t = threadIdx.x;
  const int tx = t % 32, ty = t / 32;            // 8 rows per pass
  const int r0 = blockIdx.y * 32, c0 = blockIdx.x * 32;
#pragma unroll
  for (int k = 0; k < 4; ++k) s[ty + 8 * k][tx] = W[(size_t)(r0 + ty + 8 * k) * C_ + c0 + tx];
  __syncthreads();
#pragma unroll
  for (int k = 0; k < 4; ++k) Wt[(size_t)(c0 + ty + 8 * k) * C_ + r0 + tx] = f2bf(s[tx][ty + 8 * k]);
}

// ---------------------------------------------------------------------------
// KW2: Wco2t[o][c] = bf16(Wco[o][1024+c]), o<80, c<1024.
// ---------------------------------------------------------------------------
__global__ void k_wco2_bf(const float* __restrict__ Wco, ushort* __restrict__ Wco2t) {
  const int i4 = (blockIdx.x * TPB + threadIdx.x) * 4;   // 80*1024 elems
  const int o = i4 >> 10, c = i4 & 1023;
  float4 v = *(const float4*)&Wco[(size_t)o * 2048 + C_ + c];
  ushort4 u;
  u.x = f2bf(v.x); u.y = f2bf(v.y); u.z = f2bf(v.z); u.w = f2bf(v.w);
  *(ushort4*)&Wco2t[(size_t)o * C_ + c] = u;
}

// ---------------------------------------------------------------------------
// K1v3: MFMA fold.  out[(b*80+n)*1024 + c] (bf16, B,N,C) =
//   sum_m adj[n,m] * X[b, c, m]       (X fp32 in B,C,N layout)
// mode 0: adjsrc = adj_bf global (80x96 bf16, prepadded).
// mode 1: adjsrc = dadj fp32 (B,80,80); tadj computed per block in LDS:
//   tadj[n][m] = Dd[n]*dadj[m][n]*Dd[m], Dd[n]=rsqrt(sum_m dadj[n][m]).
// Block: one b, 128 c's. D(128c x 80n) = A(X: 128c x 96m) * B(adj^T: 96m x 80n).
// 16x16x32 MFMA; 4 waves, each 2 c-tiles x 5 n-tiles, K=96 (3 steps).
// ---------------------------------------------------------------------------
__global__ __launch_bounds__(256) void k_fold_mfma(const float* __restrict__ X,
                                                   const void* __restrict__ adjsrc,
                                                   ushort* __restrict__ outp, int mode) {
  __shared__ __align__(16) ushort sX[128][104];     // rows c, cols m (pad->104, b128 2-way free)
  __shared__ __align__(16) ushort sAdj[80][104];    // rows n, cols m
  __shared__ float sD[N_];
  const int t = threadIdx.x;
  const int b  = blockIdx.x >> 3;
  const int c0 = (blockIdx.x & 7) * 128;

  // ---- adjacency -> sAdj (bf16, m 80..95 zero) ----
  if (mode == 0) {
    const ushort* ab = (const ushort*)adjsrc;
    for (int i = t; i < (N_ * 96) / 4; i += TPB) {
      ushort4 v = *(const ushort4*)&ab[i * 4];
      *(ushort4*)&sAdj[(i * 4) / 96][(i * 4) % 96] = v;
    }
    __syncthreads();
  } else {
    float* sF = (float*)&sX[0][0];                  // 80*80 fp32 = 25.6KB <= sX
    const float* db = (const float*)adjsrc + (size_t)b * NN;
    for (int i = t; i < NN / 4; i += TPB) *(float4*)&sF[i * 4] = *(const float4*)&db[i * 4];
    __syncthreads();
    if (t < N_) { float s = 0.f; for (int m = 0; m < N_; ++m) s += sF[t * N_ + m]; sD[t] = rsqrtf(s); }
    __syncthreads();
    for (int i = t; i < N_ * 96; i += TPB) {
      const int n = i / 96, m = i % 96;
      sAdj[n][m] = f2bf((m < N_) ? sF[m * N_ + n] * sD[n] * sD[m] : 0.0f);
    }
    __syncthreads();                                 // before sX overwrite
  }

  // ---- stage X (128 rows x 80 m) fp32 -> bf16; zero pad m 80..95 ----
  const float* Xb = X + ((size_t)b * C_ + c0) * N_;
  for (int i = t; i < (128 * N_) / 4; i += TPB) {
    float4 v = *(const float4*)&Xb[i * 4];
    const int r = (i * 4) / N_, m = (i * 4) % N_;
    ushort4 u; u.x = f2bf(v.x); u.y = f2bf(v.y); u.z = f2bf(v.z); u.w = f2bf(v.w);
    *(ushort4*)&sX[r][m] = u;
  }
  for (int i = t; i < (128 * 16) / 4; i += TPB) {
    const int r = i / 4, m = 80 + (i % 4) * 4;
    ushort4 z; z.x = 0; z.y = 0; z.z = 0; z.w = 0;
    *(ushort4*)&sX[r][m] = z;
  }
  __syncthreads();

  const int lane = t & 63, wid = t >> 6;
  const int l16 = lane & 15, lq = lane >> 4;
  f32x4 acc[2][5];
#pragma unroll
  for (int i = 0; i < 2; ++i)
#pragma unroll
    for (int j = 0; j < 5; ++j) { f32x4 z = {0.f, 0.f, 0.f, 0.f}; acc[i][j] = z; }
  bf16x8 af[2][3], bfr[5][3];
#pragma unroll
  for (int i = 0; i < 2; ++i)
#pragma unroll
    for (int kk = 0; kk < 3; ++kk)
      af[i][kk] = *(const bf16x8*)&sX[wid * 32 + i * 16 + l16][kk * 32 + lq * 8];
#pragma unroll
  for (int j = 0; j < 5; ++j)
#pragma unroll
    for (int kk = 0; kk < 3; ++kk)
      bfr[j][kk] = *(const bf16x8*)&sAdj[j * 16 + l16][kk * 32 + lq * 8];
#pragma unroll
  for (int i = 0; i < 2; ++i)
#pragma unroll
    for (int j = 0; j < 5; ++j)
#pragma unroll
      for (int kk = 0; kk < 3; ++kk)
        acc[i][j] = __builtin_amdgcn_mfma_f32_16x16x32_bf16(af[i][kk], bfr[j][kk], acc[i][j], 0, 0, 0);

  // ---- epilogue: D[row=c_local (lq*4+reg)][col=n (l16)] -> (B,N,C) ushort4 ----
  ushort* ob = outp + (size_t)b * CN;
#pragma unroll
  for (int i = 0; i < 2; ++i) {
    const int c = c0 + wid * 32 + i * 16 + lq * 4;
#pragma unroll
    for (int j = 0; j < 5; ++j) {
      const int n = j * 16 + l16;
      ushort4 u;
      u.x = f2bf(acc[i][j][0]); u.y = f2bf(acc[i][j][1]);
      u.z = f2bf(acc[i][j][2]); u.w = f2bf(acc[i][j][3]);
      *(ushort4*)&ob[(size_t)n * C_ + c] = u;
    }
  }
}

// ---------------------------------------------------------------------------
// K2: MFMA GEMM. A: 20480 x 1024 bf16 row-major. Bt: 1024 x 1024 bf16 row-major.
// out[b, o, n] (B,C,N) = sum_k A[m=(b,n)][k] * Bt[o][k];  out_bf: 1 -> bf16 store.
// ---------------------------------------------------------------------------
__global__ __launch_bounds__(256) void k_gemm_mfma(const ushort* __restrict__ A,
                                                   const ushort* __restrict__ Bt,
                                                   void* __restrict__ outp, int out_bf) {
  __shared__ ushort smA[128 * 32];
  __shared__ ushort smB[128 * 32];
  const int t = threadIdx.x;
  const int lane = t & 63, wid = t >> 6;
  const int m0 = blockIdx.y * 128, o0 = blockIdx.x * 128;
  const int wm = wid & 1, wn = wid >> 1;
  const int rto = t >> 2, ch = t & 3;
  const size_t gA0 = (size_t)(m0 + rto) * C_ + (size_t)ch * 8;
  const size_t gB0 = (size_t)(o0 + rto) * C_ + (size_t)ch * 8;
  ushort* ldsA = smA + wid * 512;
  ushort* ldsB = smB + wid * 512;
  const int l16 = lane & 15, lq = lane >> 4;
  const int raOff = (wm * 64 + l16) * 32 + lq * 8;
  const int rbOff = (wn * 64 + l16) * 32 + lq * 8;
  f32x4 zero = {0.f, 0.f, 0.f, 0.f};
  f32x4 acc[4][4];
#pragma unroll
  for (int i = 0; i < 4; ++i)
#pragma unroll
    for (int j = 0; j < 4; ++j) acc[i][j] = zero;
  for (int k0 = 0; k0 < C_; k0 += 32) {
    load_lds16(A  + gA0 + k0,              ldsA);
    load_lds16(A  + gA0 + 64 * C_ + k0,    ldsA + 2048);
    load_lds16(Bt + gB0 + k0,              ldsB);
    load_lds16(Bt + gB0 + 64 * C_ + k0,    ldsB + 2048);
    __syncthreads();
    bf16x8 af[4], bfr[4];
#pragma unroll
    for (int i = 0; i < 4; ++i) af[i]  = *(const bf16x8*)&smA[raOff + i * 512];
#pragma unroll
    for (int j = 0; j < 4; ++j) bfr[j] = *(const bf16x8*)&smB[rbOff + j * 512];
#pragma unroll
    for (int i = 0; i < 4; ++i)
#pragma unroll
      for (int j = 0; j < 4; ++j)
        acc[i][j] = __builtin_amdgcn_mfma_f32_16x16x32_bf16(af[i], bfr[j], acc[i][j], 0, 0, 0);
    __syncthreads();
  }
  const int og0 = o0 + wn * 64 + l16;
#pragma unroll
  for (int i = 0; i < 4; ++i) {
    const int mg = m0 + wm * 64 + i * 16 + lq * 4;
    const int b  = mg / 80;
    const int n0 = mg - b * 80;
#pragma unroll
    for (int j = 0; j < 4; ++j) {
      const int og = og0 + j * 16;
      const size_t off = (size_t)b * CN + (size_t)og * N_ + n0;
      if (out_bf) {
        ushort4 v;
        v.x = f2bf(acc[i][j][0]); v.y = f2bf(acc[i][j][1]);
        v.z = f2bf(acc[i][j][2]); v.w = f2bf(acc[i][j][3]);
        *(ushort4*)((ushort*)outp + off) = v;
      } else {
        *(f32x4*)((float*)outp + off) = acc[i][j];
      }
    }
  }
}

// ---------------------------------------------------------------------------
// K2b: dadj MFMA GEMM. A: x2t bf16 (M=20480, K=1024). Bw: Wco2t bf16 (80,1024).
// dadj[b,o,n] = go[b,o] + sum_k A[m=(b,n)][k]*Bw[o][k]. 128-row tile, 160 blocks.
// ---------------------------------------------------------------------------
__global__ __launch_bounds__(256) void k_dadj_mfma(const ushort* __restrict__ A,
                                                   const ushort* __restrict__ Bw,
                                                   const float* __restrict__ go,
                                                   float* __restrict__ dadj) {
  __shared__ ushort smA[128 * 32];
  __shared__ ushort smB[80 * 32];
  const int t = threadIdx.x;
  const int lane = t & 63, wid = t >> 6;
  const int m0 = blockIdx.x * 128;
  const int rto = t >> 2, ch = t & 3;
  const size_t gA0 = (size_t)(m0 + rto) * C_ + (size_t)ch * 8;
  ushort* ldsA = smA + wid * 512;
  const int l16 = lane & 15, lq = lane >> 4;
  const int wrow = wid * 32;
  f32x4 zero = {0.f, 0.f, 0.f, 0.f};
  f32x4 acc[2][5];
#pragma unroll
  for (int i = 0; i < 2; ++i)
#pragma unroll
    for (int j = 0; j < 5; ++j) acc[i][j] = zero;
  for (int k0 = 0; k0 < C_; k0 += 32) {
    load_lds16(A + gA0 + k0,            ldsA);
    load_lds16(A + gA0 + 64 * C_ + k0,  ldsA + 2048);
    {
      const int idx = t;                               // 320 chunks of 16B
      uint4 v = *(const uint4*)&Bw[(size_t)(idx >> 2) * C_ + k0 + (idx & 3) * 8];
      *(uint4*)&smB[idx * 8] = v;
      if (t < 64) {
        const int idx2 = 256 + t;
        uint4 v2 = *(const uint4*)&Bw[(size_t)(idx2 >> 2) * C_ + k0 + (idx2 & 3) * 8];
        *(uint4*)&smB[idx2 * 8] = v2;
      }
    }
    __syncthreads();
    bf16x8 af[2], bfr[5];
#pragma unroll
    for (int i = 0; i < 2; ++i) af[i]  = *(const bf16x8*)&smA[(wrow + i * 16 + l16) * 32 + lq * 8];
#pragma unroll
    for (int j = 0; j < 5; ++j) bfr[j] = *(const bf16x8*)&smB[(j * 16 + l16) * 32 + lq * 8];
#pragma unroll
    for (int i = 0; i < 2; ++i)
#pragma unroll
      for (int j = 0; j < 5; ++j)
        acc[i][j] = __builtin_amdgcn_mfma_f32_16x16x32_bf16(af[i], bfr[j], acc[i][j], 0, 0, 0);
    __syncthreads();
  }
#pragma unroll
  for (int i = 0; i < 2; ++i) {
    const int mg = m0 + wrow + i * 16 + lq * 4;
    const int b  = mg / 80;
    const int n0 = mg - b * 80;
    const float* gob = go + b * N_;
#pragma unroll
    for (int j = 0; j < 5; ++j) {
      const int o = j * 16 + l16;
      const float g = gob[o];
      f32x4 v = acc[i][j];
      v[0] += g; v[1] += g; v[2] += g; v[3] += g;
      *(f32x4*)&dadj[(size_t)b * NN + (size_t)o * N_ + n0] = v;
    }
  }
}

// ---------------------------------------------------------------------------
// K3: BN stats per channel over (b,n) — fp32 (B,C,N) input, float4 loads.
// ---------------------------------------------------------------------------
__global__ void k_bn_stats(const float* __restrict__ X, float* __restrict__ mu, float* __restrict__ rstd) {
  const int c = blockIdx.x, t = threadIdx.x;
  const float* base = X + (long)c * N_;
  float s = 0.f, sq = 0.f;
  for (int i4 = t; i4 < BNr / 4; i4 += TPB) {
    const int b = i4 / 20, n0 = (i4 % 20) * 4;
    float4 v = *(const float4*)&base[(long)b * CN + n0];
    s += v.x + v.y + v.z + v.w;
    sq += v.x * v.x + v.y * v.y + v.z * v.z + v.w * v.w;
  }
  __shared__ float rs[TPB], rq[TPB];
  rs[t] = s; rq[t] = sq; __syncthreads();
  for (int o = 128; o > 0; o >>= 1) { if (t < o) { rs[t] += rs[t + o]; rq[t] += rq[t + o]; } __syncthreads(); }
  if (t == 0) {
    const float m = rs[0] / BNr;
    const float var = rq[0] / BNr - m * m;
    mu[c] = m;
    rstd[c] = rsqrtf(var + EPSf);
  }
}

// K3b: same, bf16 (B,C,N) input.
__global__ void k_bn_stats_bf(const ushort* __restrict__ X, float* __restrict__ mu, float* __restrict__ rstd) {
  const int c = blockIdx.x, t = threadIdx.x;
  const ushort* base = X + (long)c * N_;
  float s = 0.f, sq = 0.f;
  for (int i4 = t; i4 < BNr / 4; i4 += TPB) {
    const int b = i4 / 20, n0 = (i4 % 20) * 4;
    ushort4 v = *(const ushort4*)&base[(long)b * CN + n0];
    const float f0 = b2f(v.x), f1 = b2f(v.y), f2 = b2f(v.z), f3 = b2f(v.w);
    s += f0 + f1 + f2 + f3;
    sq += f0 * f0 + f1 * f1 + f2 * f2 + f3 * f3;
  }
  __shared__ float rs[TPB], rq[TPB];
  rs[t] = s; rq[t] = sq; __syncthreads();
  for (int o = 128; o > 0; o >>= 1) { if (t < o) { rs[t] += rs[t + o]; rq[t] += rq[t + o]; } __syncthreads(); }
  if (t == 0) {
    const float m = rs[0] / BNr;
    const float var = rq[0] / BNr - m * m;
    mu[c] = m;
    rstd[c] = rsqrtf(var + EPSf);
  }
}

// ---------------------------------------------------------------------------
// K4: x2 = x + leaky(bn(hT_bf16)) elementwise in (B,C,N).
// ---------------------------------------------------------------------------
__global__ void k_x2(const float* __restrict__ x, const ushort* __restrict__ hT,
                     const float* __restrict__ g, const float* __restrict__ be,
                     const float* __restrict__ mu, const float* __restrict__ rstd,
                     float* __restrict__ x2) {
  const long i = ((long)blockIdx.x * TPB + threadIdx.x) * 4;
  const int c = (int)((i / N_) % C_);
  ushort4 hu = *(const ushort4*)&hT[i];
  const float4 xv = *(const float4*)&x[i];
  const float gm = g[c] * rstd[c], m = mu[c], bb = be[c];
  float4 o;
  o.x = xv.x + leakyf(gm * (b2f(hu.x) - m) + bb);
  o.y = xv.y + leakyf(gm * (b2f(hu.y) - m) + bb);
  o.z = xv.z + leakyf(gm * (b2f(hu.z) - m) + bb);
  o.w = xv.w + leakyf(gm * (b2f(hu.w) - m) + bb);
  *(float4*)&x2[i] = o;
}

// ---------------------------------------------------------------------------
// K4b: x2t[b,n,c] = bf16(x2[b,c,n]) — transpose to MFMA A layout.
// ---------------------------------------------------------------------------
__global__ __launch_bounds__(256) void k_x2t(const float* __restrict__ x2, ushort* __restrict__ x2t) {
  __shared__ float s[64][84];
  const int t = threadIdx.x;
  const long row0 = (long)blockIdx.x * 64;
  const int b = (int)(row0 >> 10), c0 = (int)(row0 & 1023);
  const float* Ab = x2 + row0 * N_;
  for (int i4 = t; i4 < (64 * N_) / 4; i4 += TPB) {
    float4 v = *(const float4*)&Ab[i4 * 4];
    *(float4*)&s[(i4 * 4) / N_][(i4 * 4) % N_] = v;
  }
  __syncthreads();
  const int tx = t % 16, ty = t / 16;
  ushort* ob = x2t + (size_t)b * CN + c0 + tx * 4;
#pragma unroll
  for (int u = 0; u < 5; ++u) {
    const int n = ty + 16 * u;
    ushort4 v;
    v.x = f2bf(s[tx * 4 + 0][n]); v.y = f2bf(s[tx * 4 + 1][n]);
    v.z = f2bf(s[tx * 4 + 2][n]); v.w = f2bf(s[tx * 4 + 3][n]);
    *(ushort4*)&ob[(size_t)n * C_] = v;
  }
}

// ---------------------------------------------------------------------------
// K5: glb0[b,c] = mean over n of x2[b,c,:]. One wave per row.
// ---------------------------------------------------------------------------
__global__ void k_glb0(const float* __restrict__ x2, float* __restrict__ glb0) {
  const int gid = blockIdx.x * TPB + threadIdx.x;
  const int wave = gid >> 6, lane = gid & 63;
  const float* r = x2 + (long)wave * N_;
  float v = r[lane];
  if (lane < 16) v += r[64 + lane];
#pragma unroll
  for (int o = 32; o > 0; o >>= 1) v += __shfl_down(v, o);
  if (lane == 0) glb0[wave] = v * (1.0f / N_);
}

// ---------------------------------------------------------------------------
// K6: small NT GEMM: out[m,n] = sum_k A[m*K+k]*Bm[n*ldb+k] + bias[n].
// ---------------------------------------------------------------------------
__global__ __launch_bounds__(256) void k_gemm_nt(const float* __restrict__ A, const float* __restrict__ Bm,
                                                 const float* __restrict__ bias, float* __restrict__ outp,
                                                 int Nn, int K, int ldb) {
  __shared__ float sA[64][20];
  __shared__ float sB[64][20];
  const int t = threadIdx.x, tx = t % 16, ty = t / 16;
  const int bm = blockIdx.y * 64, bn = blockIdx.x * 64;
  const int lr = t / 4, lk = (t % 4) * 4;
  float acc[4][4] = {};
  for (int k0 = 0; k0 < K; k0 += 16) {
    float4 av = *(const float4*)&A[(long)(bm + lr) * K + k0 + lk];
    sA[lr][lk + 0] = av.x; sA[lr][lk + 1] = av.y; sA[lr][lk + 2] = av.z; sA[lr][lk + 3] = av.w;
    float4 bv = make_float4(0.f, 0.f, 0.f, 0.f);
    if (bn + lr < Nn) bv = *(const float4*)&Bm[(long)(bn + lr) * ldb + k0 + lk];
    sB[lr][lk + 0] = bv.x; sB[lr][lk + 1] = bv.y; sB[lr][lk + 2] = bv.z; sB[lr][lk + 3] = bv.w;
    __syncthreads();
#pragma unroll
    for (int k = 0; k < 16; ++k) {
      float a[4], b[4];
#pragma unroll
      for (int i = 0; i < 4; ++i) a[i] = sA[ty * 4 + i][k];
#pragma unroll
      for (int j = 0; j < 4; ++j) b[j] = sB[tx * 4 + j][k];
#pragma unroll
      for (int i = 0; i < 4; ++i)
#pragma unroll
        for (int j = 0; j < 4; ++j) acc[i][j] += a[i] * b[j];
    }
    __syncthreads();
  }
#pragma unroll
  for (int j = 0; j < 4; ++j) {
    const int n = bn + tx * 4 + j;
    if (n < Nn) {
      const float bs = bias[n];
#pragma unroll
      for (int i = 0; i < 4; ++i) outp[(long)(bm + ty * 4 + i) * Nn + n] = acc[i][j] + bs;
    }
  }
}

// ---------------------------------------------------------------------------
// K7: BN over batch (256 rows) per channel + leaky.
// ---------------------------------------------------------------------------
__global__ void k_bng(const float* __restrict__ glb1, const float* __restrict__ gg,
                      const float* __restrict__ gb, float* __restrict__ glbf) {
  const int c = blockIdx.x, t = threadIdx.x;
  const float v = glb1[(long)t * C_ + c];
  __shared__ float rs[TPB], rq[TPB];
  rs[t] = v; rq[t] = v * v; __syncthreads();
  for (int o = 128; o > 0; o >>= 1) { if (t < o) { rs[t] += rs[t + o]; rq[t] += rq[t + o]; } __syncthreads(); }
  __shared__ float sm, sr;
  if (t == 0) { const float m = rs[0] / B_; const float var = rq[0] / B_ - m * m; sm = m; sr = rsqrtf(var + EPSf); }
  __syncthreads();
  glbf[(long)t * C_ + c] = leakyf(gg[c] * (v - sm) * sr + gb[c]);
}

// ---------------------------------------------------------------------------
// K9/K10/K11: global minmax of dadj (2-pass) + normalize in place.
// ---------------------------------------------------------------------------
__global__ void k_minmax1(const float* __restrict__ d, float* __restrict__ bmin, float* __restrict__ bmax) {
  const int t = threadIdx.x;
  float lo = 3.4e38f, hi = -3.4e38f;
  for (long i = (long)blockIdx.x * TPB + t; i < BNN; i += (long)512 * TPB) {
    const float v = d[i]; lo = fminf(lo, v); hi = fmaxf(hi, v);
  }
  __shared__ float rl[TPB], rh[TPB];
  rl[t] = lo; rh[t] = hi; __syncthreads();
  for (int o = 128; o > 0; o >>= 1) { if (t < o) { rl[t] = fminf(rl[t], rl[t + o]); rh[t] = fmaxf(rh[t], rh[t + o]); } __syncthreads(); }
  if (t == 0) { bmin[blockIdx.x] = rl[0]; bmax[blockIdx.x] = rh[0]; }
}

__global__ void k_minmax2(const float* __restrict__ bmin, const float* __restrict__ bmax, float* __restrict__ dmm) {
  const int t = threadIdx.x;
  float lo = fminf(bmin[t], bmin[t + 256]);
  float hi = fmaxf(bmax[t], bmax[t + 256]);
  __shared__ float rl[TPB], rh[TPB];
  rl[t] = lo; rh[t] = hi; __syncthreads();
  for (int o = 128; o > 0; o >>= 1) { if (t < o) { rl[t] = fminf(rl[t], rl[t + o]); rh[t] = fmaxf(rh[t], rh[t + o]); } __syncthreads(); }
  if (t == 0) { dmm[0] = rl[0]; dmm[1] = 1.0f / (rh[0] - rl[0]); }
}

__global__ void k_dadjnorm(float* __restrict__ d, const float* __restrict__ dmm) {
  const long i = ((long)blockIdx.x * TPB + threadIdx.x) * 4;
  const float lo = dmm[0], inv = dmm[1];
  float4 v = *(const float4*)&d[i];
  v.x = (v.x - lo) * inv; v.y = (v.y - lo) * inv; v.z = (v.z - lo) * inv; v.w = (v.w - lo) * inv;
  *(float4*)&d[i] = v;
}

// ---------------------------------------------------------------------------
// K12: loss per batch.
// ---------------------------------------------------------------------------
__global__ void k_loss(const float* __restrict__ dadj, const float* __restrict__ sadj,
                       const float* __restrict__ out1, float* __restrict__ lossa) {
  const int b = blockIdx.x, t = threadIdx.x;
  const float* db = dadj + (long)b * NN;
  const float* o1 = out1 + b * N_;
  float p2 = 0.f;
  for (int i = t; i < NN; i += TPB) { const float d = db[i] - sadj[i]; p2 += d * d; }
  float p1 = 0.f;
  if (t < N_) {
    float acc = 0.f;
    for (int n = 0; n < N_; ++n) acc += o1[n] * db[n * N_ + t];
    const float d = o1[t] - acc * (1.0f / N_);
    p1 = d * d;
  }
  __shared__ float red[TPB];
  __shared__ float s2;
  red[t] = p2; __syncthreads();
  for (int o = 128; o > 0; o >>= 1) { if (t < o) red[t] += red[t + o]; __syncthreads(); }
  if (t == 0) s2 = red[0];
  __syncthreads();
  red[t] = p1; __syncthreads();
  for (int o = 128; o > 0; o >>= 1) { if (t < o) red[t] += red[t + o]; __syncthreads(); }
  if (t == 0) atomicAdd(lossa, sqrtf(s2) + sqrtf(red[0]));
}

// ---------------------------------------------------------------------------
// K14: final BN + leaky in place on d_out (B,C,N); writes loss scalar.
// ---------------------------------------------------------------------------
__global__ void k_final(float* __restrict__ outp, const float* __restrict__ g, const float* __restrict__ be,
                        const float* __restrict__ mu, const float* __restrict__ rstd,
                        const float* __restrict__ lossa) {
  const long i = ((long)blockIdx.x * TPB + threadIdx.x) * 4;
  const int c = (int)((i / N_) % C_);
  float4 v = *(const float4*)&outp[i];
  const float gm = g[c] * rstd[c], m = mu[c], bb = be[c];
  v.x = leakyf(gm * (v.x - m) + bb);
  v.y = leakyf(gm * (v.y - m) + bb);
  v.z = leakyf(gm * (v.z - m) + bb);
  v.w = leakyf(gm * (v.w - m) + bb);
  *(float4*)&outp[i] = v;
  if (blockIdx.x == 0 && threadIdx.x == 0) outp[BCN] = *lossa;
}

// ---------------------------------------------------------------------------
extern "C" void kernel_launch(void* const* d_in, const int* in_sizes, int n_in,
                              void* d_out, int out_size, void* d_ws, size_t ws_size,
                              hipStream_t stream) {
  const float* x    = (const float*)d_in[0];
  const float* out1 = (const float*)d_in[1];
  const float* ap   = (const float*)d_in[2];
  const float* Ws   = (const float*)d_in[3];
  const float* Wd   = (const float*)d_in[4];
  const float* Wg   = (const float*)d_in[5];
  const float* bg   = (const float*)d_in[6];
  const float* Wco  = (const float*)d_in[7];
  const float* bco  = (const float*)d_in[8];
  const float* bn_g  = (const float*)d_in[9];
  const float* bn_b  = (const float*)d_in[10];
  const float* bng_g = (const float*)d_in[11];
  const float* bng_b = (const float*)d_in[12];
  float* out = (float*)d_out;

  float* w = (float*)d_ws;
  float* sadj  = w;                    // 6400
  float* dadj  = sadj + NN;            // 1638400
  float* glb0  = dadj + BNN;           // 262144
  float* glb1  = glb0 + B_ * C_;       // 262144
  float* glbf  = glb1 + B_ * C_;       // 262144
  float* go    = glbf + B_ * C_;       // 20480
  float* mu1   = go + BNr;             // 1024
  float* rstd1 = mu1 + C_;             // 1024
  float* mu2   = rstd1 + C_;           // 1024
  float* rstd2 = mu2 + C_;             // 1024
  float* bmin  = rstd2 + C_;           // 512
  float* bmax  = bmin + 512;           // 512
  float* dmm   = bmax + 512;           // 2
  float* lossa = dmm + 2;              // 1
  ushort* ub   = (ushort*)(((uintptr_t)(lossa + 1) + 255) & ~(uintptr_t)255);
  ushort* xa_bf  = ub;                    // BCN bf16 (B,N,C) — reused for xt
  ushort* hT_bf  = xa_bf + BCN;           // BCN bf16 (B,C,N); later reused as x2t
  ushort* Wts    = hT_bf + BCN;           // 1M bf16 (O,C)
  ushort* Wtd    = Wts + (size_t)C_ * C_; // 1M bf16 (O,C)
  ushort* Wco2t  = Wtd + (size_t)C_ * C_; // 80K bf16 (80,1024)
  ushort* adj_bf = Wco2t + (size_t)N_ * C_; // 80x96 bf16 prepadded
  ushort* x2t_bf = hT_bf;                 // alias: hT dead after k_x2

  // ---- prep ----
  k_prep_adj<<<1, TPB, 0, stream>>>(ap, sadj, adj_bf, lossa);
  k_w_bf_t<<<dim3(32, 32), TPB, 0, stream>>>(Ws, Wts);
  k_w_bf_t<<<dim3(32, 32), TPB, 0, stream>>>(Wd, Wtd);
  k_wco2_bf<<<(N_ * C_) / (4 * TPB), TPB, 0, stream>>>(Wco, Wco2t);

  // ---- static GCN ----
  k_fold_mfma<<<B_ * 8, TPB, 0, stream>>>(x, adj_bf, xa_bf, 0);
  k_gemm_mfma<<<dim3(C_ / 128, BNr / 128), TPB, 0, stream>>>(xa_bf, Wts, hT_bf, 1);
  k_bn_stats_bf<<<C_, TPB, 0, stream>>>(hT_bf, mu1, rstd1);
  k_x2<<<(int)(BCN / (4 * TPB)), TPB, 0, stream>>>(x, hT_bf, bn_g, bn_b, mu1, rstd1, out);

  // ---- dynamic graph construction ----
  k_x2t<<<(B_ * C_) / 64, TPB, 0, stream>>>(out, x2t_bf);
  k_glb0<<<(B_ * C_ * 64) / TPB, TPB, 0, stream>>>(out, glb0);
  k_gemm_nt<<<dim3(C_ / 64, B_ / 64), TPB, 0, stream>>>(glb0, Wg, bg, glb1, C_, C_, C_);
  k_bng<<<C_, TPB, 0, stream>>>(glb1, bng_g, bng_b, glbf);
  k_gemm_nt<<<dim3(2, B_ / 64), TPB, 0, stream>>>(glbf, Wco, bco, go, N_, C_, 2 * C_);
  k_dadj_mfma<<<BNr / 128, TPB, 0, stream>>>(x2t_bf, Wco2t, go, dadj);
  k_minmax1<<<512, TPB, 0, stream>>>(dadj, bmin, bmax);
  k_minmax2<<<1, TPB, 0, stream>>>(bmin, bmax, dmm);
  k_dadjnorm<<<BNN / (4 * TPB), TPB, 0, stream>>>(dadj, dmm);

  // ---- adjacency loss ----
  k_loss<<<B_, TPB, 0, stream>>>(dadj, sadj, out1, lossa);

  // ---- dynamic GCN ----
  k_fold_mfma<<<B_ * 8, TPB, 0, stream>>>(out, dadj, xa_bf, 1);   // tadj folded in
  k_gemm_mfma<<<dim3(C_ / 128, BNr / 128), TPB, 0, stream>>>(xa_bf, Wtd, out, 0);
  k_bn_stats<<<C_, TPB, 0, stream>>>(out, mu2, rstd2);
  k_final<<<(int)(BCN / (4 * TPB)), TPB, 0, stream>>>(out, bn_g, bn_b, mu2, rstd2, lossa);
}